// Round 5
// baseline (217.610 us; speedup 1.0000x reference)
//
#include <hip/hip_runtime.h>
#include <math.h>

__device__ __forceinline__ int refl256(int t) {
    t = t < 0 ? -t : t;
    return t > 255 ? 510 - t : t;
}

// ---------------- stage 1: p=1, NH=6, vertical-pair + fused batch-max ------
__global__ __launch_bounds__(256)
void attn_p1v(const float* __restrict__ x, const float* __restrict__ w,
              const float* __restrict__ bq, const float* __restrict__ hw,
              float* __restrict__ out, float* __restrict__ pmax)
{
    int t = blockIdx.x * 256 + threadIdx.x;   // 131072 threads: 4b x 128yp x 256x
    int xx = t & 255, yp = (t >> 8) & 127, bb = t >> 15;
    int y0 = yp * 2;
    const float* xb = x + bb * 196608;
    int rs[4], cs[3];
#pragma unroll
    for (int dr = 0; dr < 4; ++dr) rs[dr] = refl256(y0 + dr - 1) << 8;
#pragma unroll
    for (int dc = 0; dc < 3; ++dc) cs[dc] = refl256(xx + dc - 1);
    float xw[4][3][3];   // [row][col][ch]
#pragma unroll
    for (int dr = 0; dr < 4; ++dr)
#pragma unroll
        for (int dc = 0; dc < 3; ++dc)
#pragma unroll
            for (int c = 0; c < 3; ++c)
                xw[dr][dc][c] = xb[c * 65536 + rs[dr] + cs[dc]];

    // fused batch-max partial (own pixels = rows 1,2, center col)
    {
        float bm = 0.f;
#pragma unroll
        for (int c = 0; c < 3; ++c)
            bm = fmaxf(bm, fmaxf(xw[1][1][c], xw[2][1][c]));
#pragma unroll
        for (int off = 32; off > 0; off >>= 1)
            bm = fmaxf(bm, __shfl_down(bm, off, 64));
        __shared__ float sm[4];
        int lane = threadIdx.x & 63, wid = threadIdx.x >> 6;
        if (lane == 0) sm[wid] = bm;
        __syncthreads();
        if (threadIdx.x == 0)
            pmax[blockIdx.x] = fmaxf(fmaxf(sm[0], sm[1]), fmaxf(sm[2], sm[3]));
    }

    float ov0[3] = {0.f, 0.f, 0.f}, ov1[3] = {0.f, 0.f, 0.f};
    const float scl = 0.57735026919f;  // 1/sqrt(3); bias == 1 for p=1
#pragma unroll 1
    for (int h = 0; h < 6; ++h) {
        float hwh = hw[h];
#pragma unroll
        for (int cc = 0; cc < 3; ++cc) {
            int oq = 9 * h + cc, ok = oq + 3, oV = oq + 6;
            float wq0 = w[oq * 3], wq1 = w[oq * 3 + 1], wq2 = w[oq * 3 + 2];
            float wk0 = w[ok * 3], wk1 = w[ok * 3 + 1], wk2 = w[ok * 3 + 2];
            float wv0 = w[oV * 3], wv1 = w[oV * 3 + 1], wv2 = w[oV * 3 + 2];
            float bk = bq[ok], bv = bq[oV];
            float kp[12], vp[12];
#pragma unroll
            for (int pos = 0; pos < 12; ++pos) {
                const float* xv = xw[pos / 3][pos % 3];
                kp[pos] = fmaf(xv[0], wk0, fmaf(xv[1], wk1, fmaf(xv[2], wk2, bk)));
                vp[pos] = fmaf(xv[0], wv0, fmaf(xv[1], wv1, fmaf(xv[2], wv2, bv)));
            }
            float q0 = fmaf(xw[1][1][0], wq0, fmaf(xw[1][1][1], wq1, fmaf(xw[1][1][2], wq2, bq[oq]))) * scl;
            float q1 = fmaf(xw[2][1][0], wq0, fmaf(xw[2][1][1], wq1, fmaf(xw[2][1][2], wq2, bq[oq]))) * scl;
            float se0 = 0.f, ac0 = 0.f, se1 = 0.f, ac1 = 0.f;
#pragma unroll
            for (int j = 0; j < 9; ++j) {
                float e0 = __expf(q0 * kp[j]);
                se0 += e0; ac0 = fmaf(e0, vp[j], ac0);
                float e1 = __expf(q1 * kp[3 + j]);
                se1 += e1; ac1 = fmaf(e1, vp[3 + j], ac1);
            }
            ov0[cc] = fmaf(hwh, ac0 / se0, ov0[cc]);
            ov1[cc] = fmaf(hwh, ac1 / se1, ov1[cc]);
        }
    }
    int pix = (y0 << 8) + xx;
    float* ob = out + bb * 196608;
#pragma unroll
    for (int cc = 0; cc < 3; ++cc) {
        ob[cc * 65536 + pix] = ov0[cc];
        ob[cc * 65536 + pix + 256] = ov1[cc];
    }
}

// ---------------- fused proj+attn for p=2 / p=3 (KV stays in LDS) ----------
// Block = WB x WB windows -> (WB+2)^2 tiles. Phase A: stage raw x tiles to
// LDS. Phase B: 3 waves each project a wave-uniform third of the NO outputs
// (scalar weight loads, xw in regs, lanes = tiles) into s_kv. Phase C: one
// thread per (window, channel) does softmax-attention out of LDS.
template<int P, int NH, int WB, int OFS, int NBLK, int NWIN>
__global__ __launch_bounds__(192)
void fused_attn(const float* __restrict__ x, const float* __restrict__ w,
                const float* __restrict__ bq, const float* __restrict__ hw,
                float* __restrict__ out)
{
    constexpr int PP = P * P, L = 3 * PP, NO = NH * 9 * PP;
    constexpr int TB = WB + 2, TT = TB * TB;
    constexpr int LP = L | 1;                 // odd stride -> conflict-free
    constexpr int PAD = OFS - P;
    constexpr int OPW = NO / 3;               // outputs per wave
    constexpr float SCL = (P == 2) ? 0.28867513459481287f : 0.19245008972987526f;

    __shared__ float s_x[TT * LP];
    __shared__ float s_kv[NO * TT];
    __shared__ float s_bias[9 * PP];

    const int tid = threadIdx.x;
    int blk = blockIdx.x;
    int bb = blk / (NBLK * NBLK);
    int r2 = blk - bb * (NBLK * NBLK);
    int by = r2 / NBLK, bx = r2 - by * NBLK;
    const int wy0 = by * WB, wx0 = bx * WB;

    if (tid < 9 * PP) {   // position bias: exp(-(dr+dc)/P)
        int j = tid / PP, pos = tid - j * PP;
        int i = pos / P, jj = pos - i * P;
        int di = j / 3, dj = j - di * 3;
        float er = (di == 0) ? (float)(P - 1 - i) : (di == 2 ? (float)i : 0.f);
        float ec = (dj == 0) ? (float)(P - 1 - jj) : (dj == 2 ? (float)jj : 0.f);
        s_bias[tid] = __expf(-(er + ec) / (float)P);
    }

    // Phase A: stage x tiles (with reflect) into LDS
    const float* xb = x + bb * 196608;
    for (int idx = tid; idx < TT * L; idx += 192) {
        int t = idx / L, l = idx - t * L;
        int trow = t / TB, tcol = t - trow * TB;
        int c = l / PP, pos = l - c * PP;
        int i = pos / P, j = pos - i * P;
        int pr = refl256((wy0 + trow) * P + i - OFS);
        int pc = refl256((wx0 + tcol) * P + j - OFS);
        s_x[t * LP + l] = xb[c * 65536 + (pr << 8) + pc];
    }
    __syncthreads();

    // Phase B: projection into s_kv[o * TT + t]
    {
        const int wave = __builtin_amdgcn_readfirstlane(tid >> 6);
        const int lane = tid & 63;
#pragma unroll 1
        for (int c0 = 0; c0 < TT; c0 += 64) {
            int t = c0 + lane;
            bool tv = t < TT;
            int ts = tv ? t : 0;
            float xw[L];
#pragma unroll
            for (int l = 0; l < L; ++l) xw[l] = s_x[ts * LP + l];
#pragma unroll 4
            for (int oi = 0; oi < OPW; ++oi) {
                int o = wave * OPW + oi;
                float acc = bq[o];
                const float* wr = w + o * L;
#pragma unroll
                for (int l = 0; l < L; ++l) acc = fmaf(xw[l], wr[l], acc);
                if (tv) s_kv[o * TT + t] = acc;
            }
        }
    }
    __syncthreads();

    // Phase C: attention per (window, channel)
    if (tid < 3 * WB * WB) {
        int c = tid / (WB * WB), wl = tid - c * (WB * WB);
        int wy = wl / WB, wx = wl - wy * WB;
        int gy = wy0 + wy, gx = wx0 + wx;
        if (gy < NWIN && gx < NWIN) {
            int tc = (wy + 1) * TB + (wx + 1);
            float oa[PP];
#pragma unroll
            for (int e = 0; e < PP; ++e) oa[e] = 0.f;
#pragma unroll 1
            for (int h = 0; h < NH; ++h) {
                int bqo = ((h * 3 + 0) * 3 + c) * PP;
                int bko = ((h * 3 + 1) * 3 + c) * PP;
                int bvo = ((h * 3 + 2) * 3 + c) * PP;
                float q[PP];
#pragma unroll
                for (int e = 0; e < PP; ++e)
                    q[e] = s_kv[(bqo + e) * TT + tc] * SCL;
                float se = 0.f;
                float tmp[PP];
#pragma unroll
                for (int e = 0; e < PP; ++e) tmp[e] = 0.f;
#pragma unroll
                for (int j = 0; j < 9; ++j) {
                    int tj = (wy + j / 3) * TB + (wx + j % 3);
                    float s = 0.f;
#pragma unroll
                    for (int e = 0; e < PP; ++e)
                        s = fmaf(q[e] * s_kv[(bko + e) * TT + tj], s_bias[j * PP + e], s);
                    float ex = __expf(s);
                    se += ex;
#pragma unroll
                    for (int e = 0; e < PP; ++e)
                        tmp[e] = fmaf(ex, s_kv[(bvo + e) * TT + tj], tmp[e]);
                }
                float f = hw[h] / se;
#pragma unroll
                for (int e = 0; e < PP; ++e) oa[e] = fmaf(f, tmp[e], oa[e]);
            }
            float* ob = out + (bb * 3 + c) * 65536;
#pragma unroll
            for (int i = 0; i < P; ++i) {
                int r = gy * P + i - PAD;
                if (PAD && r < 0) continue;
#pragma unroll
                for (int jj = 0; jj < P; ++jj) {
                    int col = gx * P + jj - PAD;
                    if (PAD && col < 0) continue;
                    ob[(r << 8) + col] = oa[i * P + jj];
                }
            }
        }
    }
}

// ---------------- conv0 (5x5, 9->3, pad 2) + final elementwise, 4px/thread --
__global__ __launch_bounds__(256)
void conv_finalv(const float* __restrict__ x, const float* __restrict__ x9,
                 const float* __restrict__ x6, const float* __restrict__ x3,
                 const float* __restrict__ cw, const float* __restrict__ cb,
                 const float* __restrict__ pmax, float* __restrict__ out)
{
    int tid = threadIdx.x;
    int bb = blockIdx.x >> 6;               // 256 blocks, 64 per batch
    __shared__ float red[128];
    __shared__ float s_g;
    if (tid < 128) red[tid] = pmax[bb * 128 + tid];
    __syncthreads();
    if (tid < 64) {
        float v = fmaxf(red[tid], red[tid + 64]);
#pragma unroll
        for (int off = 32; off > 0; off >>= 1)
            v = fmaxf(v, __shfl_down(v, off, 64));
        if (tid == 0) s_g = v;
    }
    __syncthreads();

    int gid = blockIdx.x * 256 + tid;       // 65536 threads, 4 px each
    int xq = (gid & 63) << 2, r = (gid >> 6) & 255;
    float a[3][4];
#pragma unroll
    for (int oc = 0; oc < 3; ++oc) {
        float b = cb[oc];
#pragma unroll
        for (int p = 0; p < 4; ++p) a[oc][p] = b;
    }
#pragma unroll 1
    for (int s = 0; s < 3; ++s) {
        const float* bp = (s == 0 ? x9 : (s == 1 ? x6 : x3)) + bb * 196608;
#pragma unroll 1
        for (int c2 = 0; c2 < 3; ++c2) {
            const float* pl = bp + c2 * 65536;
            const float* wp = cw + (s * 3 + c2) * 25;   // uniform -> s_load
#pragma unroll
            for (int ky = 0; ky < 5; ++ky) {
                int rr = r + ky - 2;
                if ((unsigned)rr >= 256u) continue;     // wave-uniform branch
                const float* row = pl + (rr << 8);
                float cv[8];
                cv[0] = (xq >= 2) ? row[xq - 2] : 0.f;
                cv[1] = (xq >= 1) ? row[xq - 1] : 0.f;
                float4 m4 = *(const float4*)(row + xq);
                cv[2] = m4.x; cv[3] = m4.y; cv[4] = m4.z; cv[5] = m4.w;
                cv[6] = (xq + 4 < 256) ? row[xq + 4] : 0.f;
                cv[7] = (xq + 5 < 256) ? row[xq + 5] : 0.f;
#pragma unroll
                for (int kx = 0; kx < 5; ++kx) {
                    float w0 = wp[ky * 5 + kx];
                    float w1 = wp[225 + ky * 5 + kx];
                    float w2 = wp[450 + ky * 5 + kx];
#pragma unroll
                    for (int p = 0; p < 4; ++p) {
                        float v = cv[kx + p];
                        a[0][p] = fmaf(v, w0, a[0][p]);
                        a[1][p] = fmaf(v, w1, a[1][p]);
                        a[2][p] = fmaf(v, w2, a[2][p]);
                    }
                }
            }
        }
    }
    float g = s_g;
    int pix = (r << 8) + xq;
    const float* xb = x + bb * 196608;
    float* ob = out + bb * 196608;
#pragma unroll
    for (int oc = 0; oc < 3; ++oc) {
        float4 xv = *(const float4*)(xb + oc * 65536 + pix);
        float4 o4;
        float x0;
        x0 = fmaxf(a[oc][0], 0.f); o4.x = fmaxf(xv.x * x0 + g - x0, 0.f);
        x0 = fmaxf(a[oc][1], 0.f); o4.y = fmaxf(xv.y * x0 + g - x0, 0.f);
        x0 = fmaxf(a[oc][2], 0.f); o4.z = fmaxf(xv.z * x0 + g - x0, 0.f);
        x0 = fmaxf(a[oc][3], 0.f); o4.w = fmaxf(xv.w * x0 + g - x0, 0.f);
        *(float4*)(ob + oc * 65536 + pix) = o4;
    }
}

extern "C" void kernel_launch(void* const* d_in, const int* in_sizes, int n_in,
                              void* d_out, int out_size, void* d_ws, size_t ws_size,
                              hipStream_t stream)
{
    const float* x   = (const float*)d_in[0];
    const float* w3  = (const float*)d_in[1];
    const float* b3  = (const float*)d_in[2];
    const float* hw3 = (const float*)d_in[3];
    const float* w6  = (const float*)d_in[4];
    const float* b6  = (const float*)d_in[5];
    const float* hw6 = (const float*)d_in[6];
    const float* w9  = (const float*)d_in[7];
    const float* b9  = (const float*)d_in[8];
    const float* hw9 = (const float*)d_in[9];
    const float* cw  = (const float*)d_in[10];
    const float* cb  = (const float*)d_in[11];

    float* ws   = (float*)d_ws;
    float* x3b  = ws;                     // 786432 floats
    float* x6b  = ws + 786432;            // 786432
    float* x9b  = ws + 1572864;           // 786432
    float* pmax = ws + 2359296;           // 512
    float* out  = (float*)d_out;

    // stage 1 (p=1) + fused batch-max partials
    attn_p1v<<<512, 256, 0, stream>>>(x, w3, b3, hw3, x3b, pmax);

    // stage 2: p=2, NH=4, WB=8 -> 10x10 tiles, 16x16 blocks/batch
    fused_attn<2, 4, 8, 2, 16, 128><<<1024, 192, 0, stream>>>(x3b, w6, b6, hw6, x6b);
    // stage 3: p=3, NH=2, WB=7 -> 9x9 tiles, 13x13 blocks/batch
    fused_attn<3, 2, 7, 5, 13, 86><<<676, 192, 0, stream>>>(x6b, w9, b9, hw9, x9b);

    conv_finalv<<<256, 256, 0, stream>>>(x, x9b, x6b, x3b, cw, cb, pmax, out);
}

// Round 6
// 211.210 us; speedup vs baseline: 1.0303x; 1.0303x over previous
//
#include <hip/hip_runtime.h>
#include <math.h>

__device__ __forceinline__ int refl256(int t) {
    t = t < 0 ? -t : t;
    return t > 255 ? 510 - t : t;
}

// ---------------- stage 1: p=1, NH=6, vertical-pair + fused batch-max ------
__global__ __launch_bounds__(256)
void attn_p1v(const float* __restrict__ x, const float* __restrict__ w,
              const float* __restrict__ bq, const float* __restrict__ hw,
              float* __restrict__ out, float* __restrict__ pmax)
{
    int t = blockIdx.x * 256 + threadIdx.x;   // 131072 threads: 4b x 128yp x 256x
    int xx = t & 255, yp = (t >> 8) & 127, bb = t >> 15;
    int y0 = yp * 2;
    const float* xb = x + bb * 196608;
    int rs[4], cs[3];
#pragma unroll
    for (int dr = 0; dr < 4; ++dr) rs[dr] = refl256(y0 + dr - 1) << 8;
#pragma unroll
    for (int dc = 0; dc < 3; ++dc) cs[dc] = refl256(xx + dc - 1);
    float xw[4][3][3];   // [row][col][ch]
#pragma unroll
    for (int dr = 0; dr < 4; ++dr)
#pragma unroll
        for (int dc = 0; dc < 3; ++dc)
#pragma unroll
            for (int c = 0; c < 3; ++c)
                xw[dr][dc][c] = xb[c * 65536 + rs[dr] + cs[dc]];

    // fused batch-max partial (own pixels = rows 1,2, center col)
    {
        float bm = 0.f;
#pragma unroll
        for (int c = 0; c < 3; ++c)
            bm = fmaxf(bm, fmaxf(xw[1][1][c], xw[2][1][c]));
#pragma unroll
        for (int off = 32; off > 0; off >>= 1)
            bm = fmaxf(bm, __shfl_down(bm, off, 64));
        __shared__ float sm[4];
        int lane = threadIdx.x & 63, wid = threadIdx.x >> 6;
        if (lane == 0) sm[wid] = bm;
        __syncthreads();
        if (threadIdx.x == 0)
            pmax[blockIdx.x] = fmaxf(fmaxf(sm[0], sm[1]), fmaxf(sm[2], sm[3]));
    }

    float ov0[3] = {0.f, 0.f, 0.f}, ov1[3] = {0.f, 0.f, 0.f};
    const float scl = 0.57735026919f;  // 1/sqrt(3); bias == 1 for p=1
#pragma unroll 1
    for (int h = 0; h < 6; ++h) {
        float hwh = hw[h];
#pragma unroll
        for (int cc = 0; cc < 3; ++cc) {
            int oq = 9 * h + cc, ok = oq + 3, oV = oq + 6;
            float wq0 = w[oq * 3], wq1 = w[oq * 3 + 1], wq2 = w[oq * 3 + 2];
            float wk0 = w[ok * 3], wk1 = w[ok * 3 + 1], wk2 = w[ok * 3 + 2];
            float wv0 = w[oV * 3], wv1 = w[oV * 3 + 1], wv2 = w[oV * 3 + 2];
            float bk = bq[ok], bv = bq[oV];
            float kp[12], vp[12];
#pragma unroll
            for (int pos = 0; pos < 12; ++pos) {
                const float* xv = xw[pos / 3][pos % 3];
                kp[pos] = fmaf(xv[0], wk0, fmaf(xv[1], wk1, fmaf(xv[2], wk2, bk)));
                vp[pos] = fmaf(xv[0], wv0, fmaf(xv[1], wv1, fmaf(xv[2], wv2, bv)));
            }
            float q0 = fmaf(xw[1][1][0], wq0, fmaf(xw[1][1][1], wq1, fmaf(xw[1][1][2], wq2, bq[oq]))) * scl;
            float q1 = fmaf(xw[2][1][0], wq0, fmaf(xw[2][1][1], wq1, fmaf(xw[2][1][2], wq2, bq[oq]))) * scl;
            float se0 = 0.f, ac0 = 0.f, se1 = 0.f, ac1 = 0.f;
#pragma unroll
            for (int j = 0; j < 9; ++j) {
                float e0 = __expf(q0 * kp[j]);
                se0 += e0; ac0 = fmaf(e0, vp[j], ac0);
                float e1 = __expf(q1 * kp[3 + j]);
                se1 += e1; ac1 = fmaf(e1, vp[3 + j], ac1);
            }
            ov0[cc] = fmaf(hwh, ac0 / se0, ov0[cc]);
            ov1[cc] = fmaf(hwh, ac1 / se1, ov1[cc]);
        }
    }
    int pix = (y0 << 8) + xx;
    float* ob = out + bb * 196608;
#pragma unroll
    for (int cc = 0; cc < 3; ++cc) {
        ob[cc * 65536 + pix] = ov0[cc];
        ob[cc * 65536 + pix + 256] = ov1[cc];
    }
}

// ---------------- fused proj+attn v2 for p=2 / p=3 (KV in LDS) -------------
// Block = 6x6 windows -> 8x8 = 64 tiles = one wave exactly. 384 threads.
// Phase A: stage x tiles to LDS (+zero s_part). Phase B: 6 waves each
// project NO/6 outputs (scalar weight loads; lane = tile) into s_kv with
// odd stride TTP=65. Phase C: threads = (head, channel, window) tuples;
// per-head softmax-attention from LDS, combined via LDS atomicAdd.
template<int P, int NH, int NBLK, int OFS, int NWIN>
__global__ __launch_bounds__(384)
void fused_attn2(const float* __restrict__ x, const float* __restrict__ w,
                 const float* __restrict__ bq, const float* __restrict__ hw,
                 float* __restrict__ out)
{
    constexpr int WB = 6, TB = 8, TT = 64, TTP = 65;
    constexpr int PP = P * P, L = 3 * PP, NO = NH * 9 * PP;
    constexpr int LP = L | 1;
    constexpr int PAD = OFS - P;
    constexpr int OPW = NO / 6;
    constexpr int NWW = WB * WB;                 // 36
    constexpr int TUP = NH * 3 * NWW;            // phase-C tuples
    constexpr int NPART = 3 * NWW * PP;
    constexpr float SCL = (P == 2) ? 0.28867513459481287f : 0.19245008972987526f;

    __shared__ float s_x[TT * LP];
    __shared__ float s_kv[NO * TTP];
    __shared__ float s_bias[9 * PP];
    __shared__ float s_part[NPART];

    const int tid = threadIdx.x;
    int blk = blockIdx.x;
    int bb = blk / (NBLK * NBLK);
    int r2 = blk - bb * (NBLK * NBLK);
    int by = r2 / NBLK, bx = r2 - by * NBLK;
    const int wy0 = by * WB, wx0 = bx * WB;

    // Phase A: bias, zero partials, stage x tiles
    if (tid < 9 * PP) {
        int j = tid / PP, pos = tid - j * PP;
        int i = pos / P, jj = pos - i * P;
        int di = j / 3, dj = j - di * 3;
        float er = (di == 0) ? (float)(P - 1 - i) : (di == 2 ? (float)i : 0.f);
        float ec = (dj == 0) ? (float)(P - 1 - jj) : (dj == 2 ? (float)jj : 0.f);
        s_bias[tid] = __expf(-(er + ec) / (float)P);
    }
    for (int idx = tid; idx < NPART; idx += 384) s_part[idx] = 0.f;
    const float* xb = x + bb * 196608;
    for (int idx = tid; idx < TT * L; idx += 384) {
        int t = idx / L, l = idx - t * L;
        int trow = t >> 3, tcol = t & 7;
        int c = l / PP, pos = l - c * PP;
        int i = pos / P, j = pos - i * P;
        int pr = refl256((wy0 + trow) * P + i - OFS);
        int pc = refl256((wx0 + tcol) * P + j - OFS);
        s_x[t * LP + l] = xb[c * 65536 + (pr << 8) + pc];
    }
    __syncthreads();

    // Phase B: projection. lane = tile (exactly 64), wave-uniform outputs.
    {
        const int wave = __builtin_amdgcn_readfirstlane(tid >> 6);
        const int lane = tid & 63;
        float xw[L];
#pragma unroll
        for (int l = 0; l < L; ++l) xw[l] = s_x[lane * LP + l];
#pragma unroll 1
        for (int oi = 0; oi < OPW; ++oi) {
            int o = wave * OPW + oi;
            float acc = bq[o];
            const float* wr = w + o * L;
#pragma unroll
            for (int l = 0; l < L; ++l) acc = fmaf(xw[l], wr[l], acc);
            s_kv[o * TTP + lane] = acc;
        }
    }
    __syncthreads();

    // Phase C: per (head, channel, window) softmax-attention
    for (int u = tid; u < TUP; u += 384) {
        int h = u / (3 * NWW);
        int rem = u - h * (3 * NWW);
        int c = rem / NWW, wl = rem - c * NWW;
        int wy = wl / WB, wx = wl - wy * WB;
        int gy = wy0 + wy, gx = wx0 + wx;
        if (gy >= NWIN || gx >= NWIN) continue;
        int tc = (wy + 1) * TB + (wx + 1);
        int bqo = ((h * 3 + 0) * 3 + c) * PP;
        int bko = ((h * 3 + 1) * 3 + c) * PP;
        int bvo = ((h * 3 + 2) * 3 + c) * PP;
        float q[PP];
#pragma unroll
        for (int e = 0; e < PP; ++e)
            q[e] = s_kv[(bqo + e) * TTP + tc] * SCL;
        float se = 0.f;
        float tmp[PP];
#pragma unroll
        for (int e = 0; e < PP; ++e) tmp[e] = 0.f;
#pragma unroll
        for (int j = 0; j < 9; ++j) {
            int tj = (wy + j / 3) * TB + (wx + j % 3);
            float s = 0.f;
#pragma unroll
            for (int e = 0; e < PP; ++e)
                s = fmaf(q[e] * s_kv[(bko + e) * TTP + tj], s_bias[j * PP + e], s);
            float ex = __expf(s);
            se += ex;
#pragma unroll
            for (int e = 0; e < PP; ++e)
                tmp[e] = fmaf(ex, s_kv[(bvo + e) * TTP + tj], tmp[e]);
        }
        float f = hw[h] / se;
        float* pp = &s_part[(c * NWW + wl) * PP];
#pragma unroll
        for (int e = 0; e < PP; ++e)
            atomicAdd(pp + e, f * tmp[e]);
    }
    __syncthreads();

    // write-out with pad clipping
    for (int idx = tid; idx < NPART; idx += 384) {
        int c = idx / (NWW * PP);
        int rem = idx - c * (NWW * PP);
        int wl = rem / PP, pos = rem - wl * PP;
        int wy = wl / WB, wx = wl - wy * WB;
        int i = pos / P, jj = pos - i * P;
        int r = (wy0 + wy) * P + i - PAD;
        int col = (wx0 + wx) * P + jj - PAD;
        if ((unsigned)r >= 256u || (unsigned)col >= 256u) continue;
        out[(bb * 3 + c) * 65536 + (r << 8) + col] = s_part[idx];
    }
}

// ---------------- conv0 (5x5, 9->3, pad 2) + final elementwise, 4px/thread --
__global__ __launch_bounds__(256)
void conv_finalv(const float* __restrict__ x, const float* __restrict__ x9,
                 const float* __restrict__ x6, const float* __restrict__ x3,
                 const float* __restrict__ cw, const float* __restrict__ cb,
                 const float* __restrict__ pmax, float* __restrict__ out)
{
    int tid = threadIdx.x;
    int bb = blockIdx.x >> 6;               // 256 blocks, 64 per batch
    __shared__ float red[128];
    __shared__ float s_g;
    if (tid < 128) red[tid] = pmax[bb * 128 + tid];
    __syncthreads();
    if (tid < 64) {
        float v = fmaxf(red[tid], red[tid + 64]);
#pragma unroll
        for (int off = 32; off > 0; off >>= 1)
            v = fmaxf(v, __shfl_down(v, off, 64));
        if (tid == 0) s_g = v;
    }
    __syncthreads();

    int gid = blockIdx.x * 256 + tid;       // 65536 threads, 4 px each
    int xq = (gid & 63) << 2, r = (gid >> 6) & 255;
    float a[3][4];
#pragma unroll
    for (int oc = 0; oc < 3; ++oc) {
        float b = cb[oc];
#pragma unroll
        for (int p = 0; p < 4; ++p) a[oc][p] = b;
    }
#pragma unroll 1
    for (int s = 0; s < 3; ++s) {
        const float* bp = (s == 0 ? x9 : (s == 1 ? x6 : x3)) + bb * 196608;
#pragma unroll 1
        for (int c2 = 0; c2 < 3; ++c2) {
            const float* pl = bp + c2 * 65536;
            const float* wp = cw + (s * 3 + c2) * 25;   // uniform -> s_load
#pragma unroll
            for (int ky = 0; ky < 5; ++ky) {
                int rr = r + ky - 2;
                if ((unsigned)rr >= 256u) continue;     // wave-uniform branch
                const float* row = pl + (rr << 8);
                float cv[8];
                cv[0] = (xq >= 2) ? row[xq - 2] : 0.f;
                cv[1] = (xq >= 1) ? row[xq - 1] : 0.f;
                float4 m4 = *(const float4*)(row + xq);
                cv[2] = m4.x; cv[3] = m4.y; cv[4] = m4.z; cv[5] = m4.w;
                cv[6] = (xq + 4 < 256) ? row[xq + 4] : 0.f;
                cv[7] = (xq + 5 < 256) ? row[xq + 5] : 0.f;
#pragma unroll
                for (int kx = 0; kx < 5; ++kx) {
                    float w0 = wp[ky * 5 + kx];
                    float w1 = wp[225 + ky * 5 + kx];
                    float w2 = wp[450 + ky * 5 + kx];
#pragma unroll
                    for (int p = 0; p < 4; ++p) {
                        float v = cv[kx + p];
                        a[0][p] = fmaf(v, w0, a[0][p]);
                        a[1][p] = fmaf(v, w1, a[1][p]);
                        a[2][p] = fmaf(v, w2, a[2][p]);
                    }
                }
            }
        }
    }
    float g = s_g;
    int pix = (r << 8) + xq;
    const float* xb = x + bb * 196608;
    float* ob = out + bb * 196608;
#pragma unroll
    for (int oc = 0; oc < 3; ++oc) {
        float4 xv = *(const float4*)(xb + oc * 65536 + pix);
        float4 o4;
        float x0;
        x0 = fmaxf(a[oc][0], 0.f); o4.x = fmaxf(xv.x * x0 + g - x0, 0.f);
        x0 = fmaxf(a[oc][1], 0.f); o4.y = fmaxf(xv.y * x0 + g - x0, 0.f);
        x0 = fmaxf(a[oc][2], 0.f); o4.z = fmaxf(xv.z * x0 + g - x0, 0.f);
        x0 = fmaxf(a[oc][3], 0.f); o4.w = fmaxf(xv.w * x0 + g - x0, 0.f);
        *(float4*)(ob + oc * 65536 + pix) = o4;
    }
}

extern "C" void kernel_launch(void* const* d_in, const int* in_sizes, int n_in,
                              void* d_out, int out_size, void* d_ws, size_t ws_size,
                              hipStream_t stream)
{
    const float* x   = (const float*)d_in[0];
    const float* w3  = (const float*)d_in[1];
    const float* b3  = (const float*)d_in[2];
    const float* hw3 = (const float*)d_in[3];
    const float* w6  = (const float*)d_in[4];
    const float* b6  = (const float*)d_in[5];
    const float* hw6 = (const float*)d_in[6];
    const float* w9  = (const float*)d_in[7];
    const float* b9  = (const float*)d_in[8];
    const float* hw9 = (const float*)d_in[9];
    const float* cw  = (const float*)d_in[10];
    const float* cb  = (const float*)d_in[11];

    float* ws   = (float*)d_ws;
    float* x3b  = ws;                     // 786432 floats
    float* x6b  = ws + 786432;            // 786432
    float* x9b  = ws + 1572864;           // 786432
    float* pmax = ws + 2359296;           // 512
    float* out  = (float*)d_out;

    // stage 1 (p=1) + fused batch-max partials
    attn_p1v<<<512, 256, 0, stream>>>(x, w3, b3, hw3, x3b, pmax);

    // stage 2: p=2, NH=4: 22x22 blocks/batch of 6x6 windows
    fused_attn2<2, 4, 22, 2, 128><<<1936, 384, 0, stream>>>(x3b, w6, b6, hw6, x6b);
    // stage 3: p=3, NH=2: 15x15 blocks/batch of 6x6 windows
    fused_attn2<3, 2, 15, 5, 86><<<900, 384, 0, stream>>>(x6b, w9, b9, hw9, x9b);

    conv_finalv<<<256, 256, 0, stream>>>(x, x9b, x6b, x3b, cw, cb, pmax, out);
}

// Round 7
// 171.531 us; speedup vs baseline: 1.2686x; 1.2313x over previous
//
#include <hip/hip_runtime.h>
#include <math.h>

__device__ __forceinline__ int refl256(int t) {
    t = t < 0 ? -t : t;
    return t > 255 ? 510 - t : t;
}

// ---------------- stage 1: p=1, NH=6, vertical-pair + fused batch-max ------
__global__ __launch_bounds__(256)
void attn_p1v(const float* __restrict__ x, const float* __restrict__ w,
              const float* __restrict__ bq, const float* __restrict__ hw,
              float* __restrict__ out, float* __restrict__ pmax)
{
    int t = blockIdx.x * 256 + threadIdx.x;   // 131072 threads: 4b x 128yp x 256x
    int xx = t & 255, yp = (t >> 8) & 127, bb = t >> 15;
    int y0 = yp * 2;
    const float* xb = x + bb * 196608;
    int rs[4], cs[3];
#pragma unroll
    for (int dr = 0; dr < 4; ++dr) rs[dr] = refl256(y0 + dr - 1) << 8;
#pragma unroll
    for (int dc = 0; dc < 3; ++dc) cs[dc] = refl256(xx + dc - 1);
    float xw[4][3][3];   // [row][col][ch]
#pragma unroll
    for (int dr = 0; dr < 4; ++dr)
#pragma unroll
        for (int dc = 0; dc < 3; ++dc)
#pragma unroll
            for (int c = 0; c < 3; ++c)
                xw[dr][dc][c] = xb[c * 65536 + rs[dr] + cs[dc]];

    // fused batch-max partial (own pixels = rows 1,2, center col)
    {
        float bm = 0.f;
#pragma unroll
        for (int c = 0; c < 3; ++c)
            bm = fmaxf(bm, fmaxf(xw[1][1][c], xw[2][1][c]));
#pragma unroll
        for (int off = 32; off > 0; off >>= 1)
            bm = fmaxf(bm, __shfl_down(bm, off, 64));
        __shared__ float sm[4];
        int lane = threadIdx.x & 63, wid = threadIdx.x >> 6;
        if (lane == 0) sm[wid] = bm;
        __syncthreads();
        if (threadIdx.x == 0)
            pmax[blockIdx.x] = fmaxf(fmaxf(sm[0], sm[1]), fmaxf(sm[2], sm[3]));
    }

    float ov0[3] = {0.f, 0.f, 0.f}, ov1[3] = {0.f, 0.f, 0.f};
    const float scl = 0.57735026919f;  // 1/sqrt(3); bias == 1 for p=1
#pragma unroll 1
    for (int h = 0; h < 6; ++h) {
        float hwh = hw[h];
#pragma unroll
        for (int cc = 0; cc < 3; ++cc) {
            int oq = 9 * h + cc, ok = oq + 3, oV = oq + 6;
            float wq0 = w[oq * 3], wq1 = w[oq * 3 + 1], wq2 = w[oq * 3 + 2];
            float wk0 = w[ok * 3], wk1 = w[ok * 3 + 1], wk2 = w[ok * 3 + 2];
            float wv0 = w[oV * 3], wv1 = w[oV * 3 + 1], wv2 = w[oV * 3 + 2];
            float bk = bq[ok], bv = bq[oV];
            float kp[12], vp[12];
#pragma unroll
            for (int pos = 0; pos < 12; ++pos) {
                const float* xv = xw[pos / 3][pos % 3];
                kp[pos] = fmaf(xv[0], wk0, fmaf(xv[1], wk1, fmaf(xv[2], wk2, bk)));
                vp[pos] = fmaf(xv[0], wv0, fmaf(xv[1], wv1, fmaf(xv[2], wv2, bv)));
            }
            float q0 = fmaf(xw[1][1][0], wq0, fmaf(xw[1][1][1], wq1, fmaf(xw[1][1][2], wq2, bq[oq]))) * scl;
            float q1 = fmaf(xw[2][1][0], wq0, fmaf(xw[2][1][1], wq1, fmaf(xw[2][1][2], wq2, bq[oq]))) * scl;
            float se0 = 0.f, ac0 = 0.f, se1 = 0.f, ac1 = 0.f;
#pragma unroll
            for (int j = 0; j < 9; ++j) {
                float e0 = __expf(q0 * kp[j]);
                se0 += e0; ac0 = fmaf(e0, vp[j], ac0);
                float e1 = __expf(q1 * kp[3 + j]);
                se1 += e1; ac1 = fmaf(e1, vp[3 + j], ac1);
            }
            ov0[cc] = fmaf(hwh, ac0 / se0, ov0[cc]);
            ov1[cc] = fmaf(hwh, ac1 / se1, ov1[cc]);
        }
    }
    int pix = (y0 << 8) + xx;
    float* ob = out + bb * 196608;
#pragma unroll
    for (int cc = 0; cc < 3; ++cc) {
        ob[cc * 65536 + pix] = ov0[cc];
        ob[cc * 65536 + pix + 256] = ov1[cc];
    }
}

// ---------------- two-phase attention for p=2 / p=3 ----------------
// Phase 1 (v3): NO LDS, no barriers. Lane = tile (direct global gather,
// lane-consecutive tiles -> stride-P coalescing, L1/L2 absorbs re-reads
// across chunk-waves). Wave = uniform chunk of output groups (scalar
// weight loads). Outputs group-major in float4 slots: kv4[g * T4 + t].
template<int P, int NH, int NWIN, int OFS, int GSU, int NCH>
__global__ __launch_bounds__(64 * NCH)
void proj3_pk(const float* __restrict__ x, const float* __restrict__ w,
              const float* __restrict__ bq, float* __restrict__ kv)
{
    constexpr int PP = P * P, L = 3 * PP, NO = NH * 9 * PP, NG = NO / GSU;
    constexpr int CPG = NG / NCH;
    constexpr int NT = NWIN + 2, T4 = 4 * NT * NT;
    int t = blockIdx.x * 64 + threadIdx.x;
    if (t >= T4) return;
    const int chunk = __builtin_amdgcn_readfirstlane((int)threadIdx.y);
    int bb = t / (NT * NT), rr = t - bb * NT * NT;
    int ty = rr / NT, tx = rr - ty * NT;
    const float* xb = x + bb * 196608;
    float xw[L];
#pragma unroll
    for (int i = 0; i < P; ++i) {
        int pr = refl256(ty * P + i - OFS) << 8;
#pragma unroll
        for (int j = 0; j < P; ++j) {
            int pc = refl256(tx * P + j - OFS);
#pragma unroll
            for (int c = 0; c < 3; ++c)
                xw[c * PP + i * P + j] = xb[c * 65536 + pr + pc];
        }
    }
    float4* dst = (float4*)kv + t + (size_t)chunk * CPG * T4;
#pragma unroll 1
    for (int g = 0; g < CPG; ++g) {
        int go = (chunk * CPG + g) * GSU;
        float acc[GSU];
#pragma unroll
        for (int e = 0; e < GSU; ++e) acc[e] = bq[go + e];
#pragma unroll
        for (int l = 0; l < L; ++l) {
            float xv = xw[l];
#pragma unroll
            for (int e = 0; e < GSU; ++e)
                acc[e] = fmaf(xv, w[(go + e) * L + l], acc[e]);
        }
        float4 o4;
        o4.x = acc[0];
        o4.y = acc[1];
        o4.z = acc[2];
        o4.w = (GSU == 4) ? acc[GSU - 1] : 0.f;
        dst[(size_t)g * T4] = o4;
    }
}

// Phase 2: one lane per (window, channel); loop heads; softmax over 9 in regs
// (no max-subtract: scores bounded). Bias = D^(er+ec), D=exp(-1/P) literal ->
// constant-folded after unroll. No LDS, no barriers.
template<int P, int NH, int NWIN, int OFS, int GSU>
__global__ __launch_bounds__(256)
void attn2_pk(const float* __restrict__ kv, const float* __restrict__ hw,
              float* __restrict__ out)
{
    constexpr int PP = P * P, NT = NWIN + 2, T4 = 4 * NT * NT, PAD = OFS - P;
    constexpr int NGP = (PP + GSU - 1) / GSU;     // float4 groups per PP (1 or 3)
    constexpr float SCL = (P == 2) ? 0.28867513459481287f : 0.19245008972987526f;
    constexpr float DD  = (P == 2) ? 0.6065306597126334f : 0.7165313105737893f; // exp(-1/P)
    float dpw[2 * P - 1];
    dpw[0] = 1.f;
#pragma unroll
    for (int k = 1; k < 2 * P - 1; ++k) dpw[k] = dpw[k - 1] * DD;

    int tid = threadIdx.x;
    int wlin = blockIdx.x * 256 + tid;
    if (wlin >= 4 * NWIN * NWIN) return;
    int c = blockIdx.y;
    int bb = wlin / (NWIN * NWIN); int rr = wlin - bb * NWIN * NWIN;
    int yy = rr / NWIN, xx = rr - yy * NWIN;
    int tbase = bb * NT * NT + yy * NT + xx;
    int tn[9];
#pragma unroll
    for (int di = 0; di < 3; ++di)
#pragma unroll
        for (int dj = 0; dj < 3; ++dj) tn[di * 3 + dj] = tbase + di * NT + dj;
    const float4* kv4 = (const float4*)kv;
    float oa[PP];
#pragma unroll
    for (int e = 0; e < PP; ++e) oa[e] = 0.f;
#pragma unroll 1
    for (int h = 0; h < NH; ++h) {
        int oq = ((h * 3 + 0) * 3 + c) * PP;
        int ok = ((h * 3 + 1) * 3 + c) * PP;
        int ov = ((h * 3 + 2) * 3 + c) * PP;
        int gq = oq / GSU, gk = ok / GSU, gv = ov / GSU;
        float q[PP];
#pragma unroll
        for (int u = 0; u < NGP; ++u) {
            float4 t4 = kv4[(size_t)(gq + u) * T4 + tn[4]];
            float g4[4] = {t4.x, t4.y, t4.z, t4.w};
#pragma unroll
            for (int e = 0; e < GSU; ++e) q[u * GSU + e] = g4[e];
        }
        float sc[9];
#pragma unroll
        for (int j = 0; j < 9; ++j) {
            int di = j / 3, dj = j - di * 3;
            float s = 0.f;
#pragma unroll
            for (int u = 0; u < NGP; ++u) {
                float4 t4 = kv4[(size_t)(gk + u) * T4 + tn[j]];
                float g4[4] = {t4.x, t4.y, t4.z, t4.w};
#pragma unroll
                for (int e = 0; e < GSU; ++e) {
                    int Pp = u * GSU + e;
                    int i = Pp / P, jj = Pp - i * P;
                    int er = (di == 0) ? (P - 1 - i) : (di == 2 ? i : 0);
                    int ec = (dj == 0) ? (P - 1 - jj) : (dj == 2 ? jj : 0);
                    s = fmaf(q[Pp] * g4[e], dpw[er + ec], s);
                }
            }
            sc[j] = s * SCL;
        }
        float se = 0.f;
#pragma unroll
        for (int j = 0; j < 9; ++j) { sc[j] = __expf(sc[j]); se += sc[j]; }
        float tmp[PP];
#pragma unroll
        for (int e = 0; e < PP; ++e) tmp[e] = 0.f;
#pragma unroll
        for (int j = 0; j < 9; ++j) {
#pragma unroll
            for (int u = 0; u < NGP; ++u) {
                float4 t4 = kv4[(size_t)(gv + u) * T4 + tn[j]];
                float g4[4] = {t4.x, t4.y, t4.z, t4.w};
#pragma unroll
                for (int e = 0; e < GSU; ++e)
                    tmp[u * GSU + e] = fmaf(sc[j], g4[e], tmp[u * GSU + e]);
            }
        }
        float f = hw[h] / se;
#pragma unroll
        for (int e = 0; e < PP; ++e) oa[e] = fmaf(f, tmp[e], oa[e]);
    }
    float* ob = out + (bb * 3 + c) * 65536;
#pragma unroll
    for (int i = 0; i < P; ++i) {
        int r = yy * P + i - PAD;
        if (PAD && r < 0) continue;
#pragma unroll
        for (int jj = 0; jj < P; ++jj) {
            int col = xx * P + jj - PAD;
            if (PAD && col < 0) continue;
            ob[(r << 8) + col] = oa[i * P + jj];
        }
    }
}

// ---------------- conv0 (5x5, 9->3, pad 2) + final elementwise, 2px/thread --
__global__ __launch_bounds__(256)
void conv_finalv2(const float* __restrict__ x, const float* __restrict__ x9,
                  const float* __restrict__ x6, const float* __restrict__ x3,
                  const float* __restrict__ cw, const float* __restrict__ cb,
                  const float* __restrict__ pmax, float* __restrict__ out)
{
    int tid = threadIdx.x;
    int bb = blockIdx.x >> 7;               // 512 blocks, 128 per batch
    __shared__ float red[128];
    __shared__ float s_g;
    if (tid < 128) red[tid] = pmax[bb * 128 + tid];
    __syncthreads();
    if (tid < 64) {
        float v = fmaxf(red[tid], red[tid + 64]);
#pragma unroll
        for (int off = 32; off > 0; off >>= 1)
            v = fmaxf(v, __shfl_down(v, off, 64));
        if (tid == 0) s_g = v;
    }
    __syncthreads();

    int gid = blockIdx.x * 256 + tid;       // 131072 threads, 2 px each
    int xp = (gid & 127) << 1, r = (gid >> 7) & 255;
    float a[3][2];
#pragma unroll
    for (int oc = 0; oc < 3; ++oc) {
        float b = cb[oc];
        a[oc][0] = b; a[oc][1] = b;
    }
#pragma unroll 1
    for (int s = 0; s < 3; ++s) {
        const float* bp = (s == 0 ? x9 : (s == 1 ? x6 : x3)) + bb * 196608;
#pragma unroll 1
        for (int c2 = 0; c2 < 3; ++c2) {
            const float* pl = bp + c2 * 65536;
            const float* wp = cw + (s * 3 + c2) * 25;   // uniform -> s_load
#pragma unroll
            for (int ky = 0; ky < 5; ++ky) {
                int rr = r + ky - 2;
                if ((unsigned)rr >= 256u) continue;     // wave-uniform-ish branch
                const float* row = pl + (rr << 8);
                float2 va = (xp >= 2) ? *(const float2*)(row + xp - 2)
                                      : make_float2(0.f, 0.f);
                float2 vb = *(const float2*)(row + xp);
                float2 vc = (xp + 2 < 256) ? *(const float2*)(row + xp + 2)
                                           : make_float2(0.f, 0.f);
                float cv[6] = {va.x, va.y, vb.x, vb.y, vc.x, vc.y};
#pragma unroll
                for (int kx = 0; kx < 5; ++kx) {
                    float w0 = wp[ky * 5 + kx];
                    float w1 = wp[225 + ky * 5 + kx];
                    float w2 = wp[450 + ky * 5 + kx];
                    float v0 = cv[kx], v1 = cv[kx + 1];
                    a[0][0] = fmaf(v0, w0, a[0][0]); a[0][1] = fmaf(v1, w0, a[0][1]);
                    a[1][0] = fmaf(v0, w1, a[1][0]); a[1][1] = fmaf(v1, w1, a[1][1]);
                    a[2][0] = fmaf(v0, w2, a[2][0]); a[2][1] = fmaf(v1, w2, a[2][1]);
                }
            }
        }
    }
    float g = s_g;
    int pix = (r << 8) + xp;
    const float* xb = x + bb * 196608;
    float* ob = out + bb * 196608;
#pragma unroll
    for (int oc = 0; oc < 3; ++oc) {
        float2 xv = *(const float2*)(xb + oc * 65536 + pix);
        float2 o2;
        float x0;
        x0 = fmaxf(a[oc][0], 0.f); o2.x = fmaxf(xv.x * x0 + g - x0, 0.f);
        x0 = fmaxf(a[oc][1], 0.f); o2.y = fmaxf(xv.y * x0 + g - x0, 0.f);
        *(float2*)(ob + oc * 65536 + pix) = o2;
    }
}

extern "C" void kernel_launch(void* const* d_in, const int* in_sizes, int n_in,
                              void* d_out, int out_size, void* d_ws, size_t ws_size,
                              hipStream_t stream)
{
    const float* x   = (const float*)d_in[0];
    const float* w3  = (const float*)d_in[1];
    const float* b3  = (const float*)d_in[2];
    const float* hw3 = (const float*)d_in[3];
    const float* w6  = (const float*)d_in[4];
    const float* b6  = (const float*)d_in[5];
    const float* hw6 = (const float*)d_in[6];
    const float* w9  = (const float*)d_in[7];
    const float* b9  = (const float*)d_in[8];
    const float* hw9 = (const float*)d_in[9];
    const float* cw  = (const float*)d_in[10];
    const float* cb  = (const float*)d_in[11];

    float* ws   = (float*)d_ws;
    float* x3b  = ws;                     // 786432 floats
    float* x6b  = ws + 786432;            // 786432
    float* x9b  = ws + 1572864;           // 786432
    float* pmax = ws + 2359296;           // 512
    float* kvb  = ws + 2359808;           // up to 9,734,400 floats (p2 KV)
    float* out  = (float*)d_out;

    // stage 1 (p=1) + fused batch-max partials
    attn_p1v<<<512, 256, 0, stream>>>(x, w3, b3, hw3, x3b, pmax);

    // stage 2: p=2, NH=4, NWIN=128, OFS=2, GSU=4, NG=36, NCH=6 -> CPG=6
    proj3_pk<2, 4, 128, 2, 4, 6><<<1057, dim3(64, 6), 0, stream>>>(x3b, w6, b6, kvb);
    attn2_pk<2, 4, 128, 2, 4><<<dim3(256, 3), 256, 0, stream>>>(kvb, hw6, x6b);
    // stage 3: p=3, NH=2, NWIN=86, OFS=5, GSU=3, NG=54, NCH=9 -> CPG=6
    proj3_pk<3, 2, 86, 5, 3, 9><<<484, dim3(64, 9), 0, stream>>>(x6b, w9, b9, kvb);
    attn2_pk<3, 2, 86, 5, 3><<<dim3(116, 3), 256, 0, stream>>>(kvb, hw9, x9b);

    conv_finalv2<<<512, 256, 0, stream>>>(x, x9b, x6b, x3b, cw, cb, pmax, out);
}

// Round 8
// 157.519 us; speedup vs baseline: 1.3815x; 1.0890x over previous
//
#include <hip/hip_runtime.h>
#include <math.h>

__device__ __forceinline__ int refl256(int t) {
    t = t < 0 ? -t : t;
    return t > 255 ? 510 - t : t;
}

// ---------------- stage 1: p=1, NH=6, pair-of-rows, head-split over y ------
// Block = (128 pair-slots, 2 head-groups). Each thread: 3 heads x 3 ch for
// pixels (y0,x),(y0+1,x). hg=1 writes partials to LDS; hg=0 combines+stores.
__global__ __launch_bounds__(256)
void attn_p1v2(const float* __restrict__ x, const float* __restrict__ w,
               const float* __restrict__ bq, const float* __restrict__ hw,
               float* __restrict__ out, float* __restrict__ pmax)
{
    const int slot = threadIdx.x;                      // 0..127
    const int hg = __builtin_amdgcn_readfirstlane((int)threadIdx.y);  // wave-uniform
    int t2 = blockIdx.x * 128 + slot;                  // pair index (131072 total)
    int xx = t2 & 255, yp = (t2 >> 8) & 127, bb = t2 >> 15;
    int y0 = yp * 2;
    const float* xb = x + bb * 196608;
    int rs[4], cs[3];
#pragma unroll
    for (int dr = 0; dr < 4; ++dr) rs[dr] = refl256(y0 + dr - 1) << 8;
#pragma unroll
    for (int dc = 0; dc < 3; ++dc) cs[dc] = refl256(xx + dc - 1);
    float xw[4][3][3];
#pragma unroll
    for (int dr = 0; dr < 4; ++dr)
#pragma unroll
        for (int dc = 0; dc < 3; ++dc)
#pragma unroll
            for (int c = 0; c < 3; ++c)
                xw[dr][dc][c] = xb[c * 65536 + rs[dr] + cs[dc]];

    // fused batch-max partial (own pixels; both hgroups redundant -> max ok)
    {
        float bm = 0.f;
#pragma unroll
        for (int c = 0; c < 3; ++c)
            bm = fmaxf(bm, fmaxf(xw[1][1][c], xw[2][1][c]));
#pragma unroll
        for (int off = 32; off > 0; off >>= 1)
            bm = fmaxf(bm, __shfl_down(bm, off, 64));
        __shared__ float sm[4];
        int flat = threadIdx.y * 128 + slot;
        if ((flat & 63) == 0) sm[flat >> 6] = bm;
        __syncthreads();
        if (flat == 0)
            pmax[blockIdx.x] = fmaxf(fmaxf(sm[0], sm[1]), fmaxf(sm[2], sm[3]));
    }

    float ov0[3] = {0.f, 0.f, 0.f}, ov1[3] = {0.f, 0.f, 0.f};
    const float scl = 0.57735026919f;  // 1/sqrt(3); bias == 1 for p=1
#pragma unroll 1
    for (int hi = 0; hi < 3; ++hi) {
        int h = hg * 3 + hi;
        float hwh = hw[h];
#pragma unroll
        for (int cc = 0; cc < 3; ++cc) {
            int oq = 9 * h + cc, ok = oq + 3, oV = oq + 6;
            float wq0 = w[oq * 3], wq1 = w[oq * 3 + 1], wq2 = w[oq * 3 + 2];
            float wk0 = w[ok * 3], wk1 = w[ok * 3 + 1], wk2 = w[ok * 3 + 2];
            float wv0 = w[oV * 3], wv1 = w[oV * 3 + 1], wv2 = w[oV * 3 + 2];
            float bk = bq[ok], bv = bq[oV];
            float kp[12], vp[12];
#pragma unroll
            for (int pos = 0; pos < 12; ++pos) {
                const float* xv = xw[pos / 3][pos % 3];
                kp[pos] = fmaf(xv[0], wk0, fmaf(xv[1], wk1, fmaf(xv[2], wk2, bk)));
                vp[pos] = fmaf(xv[0], wv0, fmaf(xv[1], wv1, fmaf(xv[2], wv2, bv)));
            }
            float q0 = fmaf(xw[1][1][0], wq0, fmaf(xw[1][1][1], wq1, fmaf(xw[1][1][2], wq2, bq[oq]))) * scl;
            float q1 = fmaf(xw[2][1][0], wq0, fmaf(xw[2][1][1], wq1, fmaf(xw[2][1][2], wq2, bq[oq]))) * scl;
            float se0 = 0.f, ac0 = 0.f, se1 = 0.f, ac1 = 0.f;
#pragma unroll
            for (int j = 0; j < 9; ++j) {
                float e0 = __expf(q0 * kp[j]);
                se0 += e0; ac0 = fmaf(e0, vp[j], ac0);
                float e1 = __expf(q1 * kp[3 + j]);
                se1 += e1; ac1 = fmaf(e1, vp[3 + j], ac1);
            }
            ov0[cc] = fmaf(hwh, ac0 / se0, ov0[cc]);
            ov1[cc] = fmaf(hwh, ac1 / se1, ov1[cc]);
        }
    }
    __shared__ float s_part[128][6];
    if (hg == 1) {
#pragma unroll
        for (int cc = 0; cc < 3; ++cc) {
            s_part[slot][cc] = ov0[cc];
            s_part[slot][3 + cc] = ov1[cc];
        }
    }
    __syncthreads();
    if (hg == 0) {
        int pix = (y0 << 8) + xx;
        float* ob = out + bb * 196608;
#pragma unroll
        for (int cc = 0; cc < 3; ++cc) {
            ob[cc * 65536 + pix] = ov0[cc] + s_part[slot][cc];
            ob[cc * 65536 + pix + 256] = ov1[cc] + s_part[slot][3 + cc];
        }
    }
}

// ---------------- two-phase attention for p=2 / p=3 ----------------
// Phase 1: NO LDS, no barriers. Lane = tile (direct global gather), wave =
// uniform chunk of output groups. Outputs group-major: kv4[g * T4 + t].
template<int P, int NH, int NWIN, int OFS, int GSU, int NCH>
__global__ __launch_bounds__(64 * NCH)
void proj3_pk(const float* __restrict__ x, const float* __restrict__ w,
              const float* __restrict__ bq, float* __restrict__ kv)
{
    constexpr int PP = P * P, L = 3 * PP, NO = NH * 9 * PP, NG = NO / GSU;
    constexpr int CPG = NG / NCH;
    constexpr int NT = NWIN + 2, T4 = 4 * NT * NT;
    int t = blockIdx.x * 64 + threadIdx.x;
    if (t >= T4) return;
    const int chunk = __builtin_amdgcn_readfirstlane((int)threadIdx.y);
    int bb = t / (NT * NT), rr = t - bb * NT * NT;
    int ty = rr / NT, tx = rr - ty * NT;
    const float* xb = x + bb * 196608;
    float xw[L];
#pragma unroll
    for (int i = 0; i < P; ++i) {
        int pr = refl256(ty * P + i - OFS) << 8;
#pragma unroll
        for (int j = 0; j < P; ++j) {
            int pc = refl256(tx * P + j - OFS);
#pragma unroll
            for (int c = 0; c < 3; ++c)
                xw[c * PP + i * P + j] = xb[c * 65536 + pr + pc];
        }
    }
    float4* dst = (float4*)kv + t + (size_t)chunk * CPG * T4;
#pragma unroll 1
    for (int g = 0; g < CPG; ++g) {
        int go = (chunk * CPG + g) * GSU;
        float acc[GSU];
#pragma unroll
        for (int e = 0; e < GSU; ++e) acc[e] = bq[go + e];
#pragma unroll
        for (int l = 0; l < L; ++l) {
            float xv = xw[l];
#pragma unroll
            for (int e = 0; e < GSU; ++e)
                acc[e] = fmaf(xv, w[(go + e) * L + l], acc[e]);
        }
        float4 o4;
        o4.x = acc[0];
        o4.y = acc[1];
        o4.z = acc[2];
        o4.w = (GSU == 4) ? acc[GSU - 1] : 0.f;
        dst[(size_t)g * T4] = o4;
    }
}

// Phase 2 (head-split): block = (128 window-slots, 2 head-groups of HPT).
// Per-group softmax-attention from global KV; combine via LDS partial.
template<int P, int NH, int NWIN, int OFS, int GSU, int HPT>
__global__ __launch_bounds__(256)
void attn3_pk(const float* __restrict__ kv, const float* __restrict__ hw,
              float* __restrict__ out)
{
    constexpr int PP = P * P, NT = NWIN + 2, T4 = 4 * NT * NT, PAD = OFS - P;
    constexpr int NGP = (PP + GSU - 1) / GSU;
    constexpr float SCL = (P == 2) ? 0.28867513459481287f : 0.19245008972987526f;
    constexpr float DD  = (P == 2) ? 0.6065306597126334f : 0.7165313105737893f; // exp(-1/P)
    float dpw[2 * P - 1];
    dpw[0] = 1.f;
#pragma unroll
    for (int k = 1; k < 2 * P - 1; ++k) dpw[k] = dpw[k - 1] * DD;

    const int slot = threadIdx.x;                       // 0..127
    const int hg = __builtin_amdgcn_readfirstlane((int)threadIdx.y);
    int wlin = blockIdx.x * 128 + slot;
    const bool active = wlin < 4 * NWIN * NWIN;
    int wsafe = active ? wlin : 0;
    int c = blockIdx.y;
    int bb = wsafe / (NWIN * NWIN); int rr = wsafe - bb * (NWIN * NWIN);
    int yy = rr / NWIN, xx = rr - yy * NWIN;
    int tbase = bb * NT * NT + yy * NT + xx;
    int tn[9];
#pragma unroll
    for (int di = 0; di < 3; ++di)
#pragma unroll
        for (int dj = 0; dj < 3; ++dj) tn[di * 3 + dj] = tbase + di * NT + dj;
    const float4* kv4 = (const float4*)kv;
    float oa[PP];
#pragma unroll
    for (int e = 0; e < PP; ++e) oa[e] = 0.f;
#pragma unroll 1
    for (int hi = 0; hi < HPT; ++hi) {
        int h = hg * HPT + hi;
        int oq = ((h * 3 + 0) * 3 + c) * PP;
        int ok = ((h * 3 + 1) * 3 + c) * PP;
        int ov = ((h * 3 + 2) * 3 + c) * PP;
        int gq = oq / GSU, gk = ok / GSU, gv = ov / GSU;
        float q[PP];
#pragma unroll
        for (int u = 0; u < NGP; ++u) {
            float4 t4 = kv4[(size_t)(gq + u) * T4 + tn[4]];
            float g4[4] = {t4.x, t4.y, t4.z, t4.w};
#pragma unroll
            for (int e = 0; e < GSU; ++e) q[u * GSU + e] = g4[e];
        }
        float sc[9];
#pragma unroll
        for (int j = 0; j < 9; ++j) {
            int di = j / 3, dj = j - di * 3;
            float s = 0.f;
#pragma unroll
            for (int u = 0; u < NGP; ++u) {
                float4 t4 = kv4[(size_t)(gk + u) * T4 + tn[j]];
                float g4[4] = {t4.x, t4.y, t4.z, t4.w};
#pragma unroll
                for (int e = 0; e < GSU; ++e) {
                    int Pp = u * GSU + e;
                    int i = Pp / P, jj = Pp - i * P;
                    int er = (di == 0) ? (P - 1 - i) : (di == 2 ? i : 0);
                    int ec = (dj == 0) ? (P - 1 - jj) : (dj == 2 ? jj : 0);
                    s = fmaf(q[Pp] * g4[e], dpw[er + ec], s);
                }
            }
            sc[j] = s * SCL;
        }
        float se = 0.f;
#pragma unroll
        for (int j = 0; j < 9; ++j) { sc[j] = __expf(sc[j]); se += sc[j]; }
        float tmp[PP];
#pragma unroll
        for (int e = 0; e < PP; ++e) tmp[e] = 0.f;
#pragma unroll
        for (int j = 0; j < 9; ++j) {
#pragma unroll
            for (int u = 0; u < NGP; ++u) {
                float4 t4 = kv4[(size_t)(gv + u) * T4 + tn[j]];
                float g4[4] = {t4.x, t4.y, t4.z, t4.w};
#pragma unroll
                for (int e = 0; e < GSU; ++e)
                    tmp[u * GSU + e] = fmaf(sc[j], g4[e], tmp[u * GSU + e]);
            }
        }
        float f = hw[h] / se;
#pragma unroll
        for (int e = 0; e < PP; ++e) oa[e] = fmaf(f, tmp[e], oa[e]);
    }
    __shared__ float s_part[128][PP];
    if (hg == 1) {
#pragma unroll
        for (int e = 0; e < PP; ++e) s_part[slot][e] = oa[e];
    }
    __syncthreads();
    if (hg == 0 && active) {
        float* ob = out + (bb * 3 + c) * 65536;
#pragma unroll
        for (int i = 0; i < P; ++i) {
            int r = yy * P + i - PAD;
            if (PAD && r < 0) continue;
#pragma unroll
            for (int jj = 0; jj < P; ++jj) {
                int col = xx * P + jj - PAD;
                if (PAD && col < 0) continue;
                int e = i * P + jj;
                ob[(r << 8) + col] = oa[e] + s_part[slot][e];
            }
        }
    }
}

// -------- conv0 (5x5, 9->3, pad 2) + final, source-split over y ------------
// Block = (128 pair-slots, 3 sources). Each thread: one source's 3 channels
// for 2 px. y=1,2 write partials to LDS; y=0 combines + final elementwise.
__global__ __launch_bounds__(384)
void conv_finalv3(const float* __restrict__ x, const float* __restrict__ x9,
                  const float* __restrict__ x6, const float* __restrict__ x3,
                  const float* __restrict__ cw, const float* __restrict__ cb,
                  const float* __restrict__ pmax, float* __restrict__ out)
{
    const int slot = threadIdx.x;                       // 0..127
    const int src = __builtin_amdgcn_readfirstlane((int)threadIdx.y);  // 0,1,2
    int bb = blockIdx.x >> 8;                           // 1024 blocks, 256/batch
    __shared__ float s_g;
    {
        int flat = threadIdx.y * 128 + slot;
        if (flat < 64) {
            const float* pm = pmax + bb * 256 + flat * 4;
            float v = fmaxf(fmaxf(pm[0], pm[1]), fmaxf(pm[2], pm[3]));
#pragma unroll
            for (int off = 32; off > 0; off >>= 1)
                v = fmaxf(v, __shfl_down(v, off, 64));
            if (flat == 0) s_g = v;
        }
    }
    int pair = (blockIdx.x & 255) * 128 + slot;         // within batch
    int xp = (pair & 127) << 1, r = pair >> 7;
    float a[3][2];
#pragma unroll
    for (int oc = 0; oc < 3; ++oc) { a[oc][0] = 0.f; a[oc][1] = 0.f; }
    const float* bp = (src == 0 ? x9 : (src == 1 ? x6 : x3)) + bb * 196608;
#pragma unroll 1
    for (int c2 = 0; c2 < 3; ++c2) {
        const float* pl = bp + c2 * 65536;
        const float* wp = cw + (src * 3 + c2) * 25;     // wave-uniform -> s_load
#pragma unroll
        for (int ky = 0; ky < 5; ++ky) {
            int rr = r + ky - 2;
            if ((unsigned)rr >= 256u) continue;
            const float* row = pl + (rr << 8);
            float2 va = (xp >= 2) ? *(const float2*)(row + xp - 2)
                                  : make_float2(0.f, 0.f);
            float2 vb = *(const float2*)(row + xp);
            float2 vc = (xp + 2 < 256) ? *(const float2*)(row + xp + 2)
                                       : make_float2(0.f, 0.f);
            float cv[6] = {va.x, va.y, vb.x, vb.y, vc.x, vc.y};
#pragma unroll
            for (int kx = 0; kx < 5; ++kx) {
                float w0 = wp[ky * 5 + kx];
                float w1 = wp[225 + ky * 5 + kx];
                float w2 = wp[450 + ky * 5 + kx];
                float v0 = cv[kx], v1 = cv[kx + 1];
                a[0][0] = fmaf(v0, w0, a[0][0]); a[0][1] = fmaf(v1, w0, a[0][1]);
                a[1][0] = fmaf(v0, w1, a[1][0]); a[1][1] = fmaf(v1, w1, a[1][1]);
                a[2][0] = fmaf(v0, w2, a[2][0]); a[2][1] = fmaf(v1, w2, a[2][1]);
            }
        }
    }
    __shared__ float s_part[2][128][6];
    if (src > 0) {
#pragma unroll
        for (int oc = 0; oc < 3; ++oc) {
            s_part[src - 1][slot][oc * 2]     = a[oc][0];
            s_part[src - 1][slot][oc * 2 + 1] = a[oc][1];
        }
    }
    __syncthreads();
    if (src == 0) {
        float g = s_g;
        int pix = (r << 8) + xp;
        const float* xb = x + bb * 196608;
        float* ob = out + bb * 196608;
#pragma unroll
        for (int oc = 0; oc < 3; ++oc) {
            float a0 = a[oc][0] + s_part[0][slot][oc * 2] + s_part[1][slot][oc * 2] + cb[oc];
            float a1 = a[oc][1] + s_part[0][slot][oc * 2 + 1] + s_part[1][slot][oc * 2 + 1] + cb[oc];
            float2 xv = *(const float2*)(xb + oc * 65536 + pix);
            float2 o2;
            float x0;
            x0 = fmaxf(a0, 0.f); o2.x = fmaxf(xv.x * x0 + g - x0, 0.f);
            x0 = fmaxf(a1, 0.f); o2.y = fmaxf(xv.y * x0 + g - x0, 0.f);
            *(float2*)(ob + oc * 65536 + pix) = o2;
        }
    }
}

extern "C" void kernel_launch(void* const* d_in, const int* in_sizes, int n_in,
                              void* d_out, int out_size, void* d_ws, size_t ws_size,
                              hipStream_t stream)
{
    const float* x   = (const float*)d_in[0];
    const float* w3  = (const float*)d_in[1];
    const float* b3  = (const float*)d_in[2];
    const float* hw3 = (const float*)d_in[3];
    const float* w6  = (const float*)d_in[4];
    const float* b6  = (const float*)d_in[5];
    const float* hw6 = (const float*)d_in[6];
    const float* w9  = (const float*)d_in[7];
    const float* b9  = (const float*)d_in[8];
    const float* hw9 = (const float*)d_in[9];
    const float* cw  = (const float*)d_in[10];
    const float* cb  = (const float*)d_in[11];

    float* ws   = (float*)d_ws;
    float* x3b  = ws;                     // 786432 floats
    float* x6b  = ws + 786432;            // 786432
    float* x9b  = ws + 1572864;           // 786432
    float* pmax = ws + 2359296;           // 1024
    float* kvb  = ws + 2360320;           // up to 9,734,400 floats (p2 KV)
    float* out  = (float*)d_out;

    // stage 1 (p=1), head-split, + fused batch-max partials
    attn_p1v2<<<1024, dim3(128, 2), 0, stream>>>(x, w3, b3, hw3, x3b, pmax);

    // stage 2: p=2, NH=4, NWIN=128, OFS=2, GSU=4, NG=36, NCH=6 -> CPG=6
    proj3_pk<2, 4, 128, 2, 4, 6><<<1057, dim3(64, 6), 0, stream>>>(x3b, w6, b6, kvb);
    attn3_pk<2, 4, 128, 2, 4, 2><<<dim3(512, 3), dim3(128, 2), 0, stream>>>(kvb, hw6, x6b);
    // stage 3: p=3, NH=2, NWIN=86, OFS=5, GSU=3, NG=54, NCH=9 -> CPG=6
    proj3_pk<3, 2, 86, 5, 3, 9><<<484, dim3(64, 9), 0, stream>>>(x6b, w9, b9, kvb);
    attn3_pk<3, 2, 86, 5, 3, 1><<<dim3(232, 3), dim3(128, 2), 0, stream>>>(kvb, hw9, x9b);

    conv_finalv3<<<1024, dim3(128, 3), 0, stream>>>(x, x9b, x6b, x3b, cw, cb, pmax, out);
}

// Round 9
// 155.525 us; speedup vs baseline: 1.3992x; 1.0128x over previous
//
#include <hip/hip_runtime.h>
#include <hip/hip_fp16.h>
#include <math.h>

__device__ __forceinline__ int refl256(int t) {
    t = t < 0 ? -t : t;
    return t > 255 ? 510 - t : t;
}

__device__ __forceinline__ void unpack4h(uint2 u, float* g4) {
    __half2 h01 = *(__half2*)&u.x, h23 = *(__half2*)&u.y;
    g4[0] = __low2float(h01); g4[1] = __high2float(h01);
    g4[2] = __low2float(h23); g4[3] = __high2float(h23);
}

// ---------------- stage 1: p=1, NH=6, pair-of-rows, head-split over y ------
__global__ __launch_bounds__(256)
void attn_p1v2(const float* __restrict__ x, const float* __restrict__ w,
               const float* __restrict__ bq, const float* __restrict__ hw,
               float* __restrict__ out, float* __restrict__ pmax)
{
    const int slot = threadIdx.x;                      // 0..127
    const int hg = __builtin_amdgcn_readfirstlane((int)threadIdx.y);  // wave-uniform
    int t2 = blockIdx.x * 128 + slot;                  // pair index (131072 total)
    int xx = t2 & 255, yp = (t2 >> 8) & 127, bb = t2 >> 15;
    int y0 = yp * 2;
    const float* xb = x + bb * 196608;
    int rs[4], cs[3];
#pragma unroll
    for (int dr = 0; dr < 4; ++dr) rs[dr] = refl256(y0 + dr - 1) << 8;
#pragma unroll
    for (int dc = 0; dc < 3; ++dc) cs[dc] = refl256(xx + dc - 1);
    float xw[4][3][3];
#pragma unroll
    for (int dr = 0; dr < 4; ++dr)
#pragma unroll
        for (int dc = 0; dc < 3; ++dc)
#pragma unroll
            for (int c = 0; c < 3; ++c)
                xw[dr][dc][c] = xb[c * 65536 + rs[dr] + cs[dc]];

    // fused batch-max partial (own pixels; both hgroups redundant -> max ok)
    {
        float bm = 0.f;
#pragma unroll
        for (int c = 0; c < 3; ++c)
            bm = fmaxf(bm, fmaxf(xw[1][1][c], xw[2][1][c]));
#pragma unroll
        for (int off = 32; off > 0; off >>= 1)
            bm = fmaxf(bm, __shfl_down(bm, off, 64));
        __shared__ float sm[4];
        int flat = threadIdx.y * 128 + slot;
        if ((flat & 63) == 0) sm[flat >> 6] = bm;
        __syncthreads();
        if (flat == 0)
            pmax[blockIdx.x] = fmaxf(fmaxf(sm[0], sm[1]), fmaxf(sm[2], sm[3]));
    }

    float ov0[3] = {0.f, 0.f, 0.f}, ov1[3] = {0.f, 0.f, 0.f};
    const float scl = 0.57735026919f;  // 1/sqrt(3); bias == 1 for p=1
#pragma unroll 1
    for (int hi = 0; hi < 3; ++hi) {
        int h = hg * 3 + hi;
        float hwh = hw[h];
#pragma unroll
        for (int cc = 0; cc < 3; ++cc) {
            int oq = 9 * h + cc, ok = oq + 3, oV = oq + 6;
            float wq0 = w[oq * 3], wq1 = w[oq * 3 + 1], wq2 = w[oq * 3 + 2];
            float wk0 = w[ok * 3], wk1 = w[ok * 3 + 1], wk2 = w[ok * 3 + 2];
            float wv0 = w[oV * 3], wv1 = w[oV * 3 + 1], wv2 = w[oV * 3 + 2];
            float bk = bq[ok], bv = bq[oV];
            float kp[12], vp[12];
#pragma unroll
            for (int pos = 0; pos < 12; ++pos) {
                const float* xv = xw[pos / 3][pos % 3];
                kp[pos] = fmaf(xv[0], wk0, fmaf(xv[1], wk1, fmaf(xv[2], wk2, bk)));
                vp[pos] = fmaf(xv[0], wv0, fmaf(xv[1], wv1, fmaf(xv[2], wv2, bv)));
            }
            float q0 = fmaf(xw[1][1][0], wq0, fmaf(xw[1][1][1], wq1, fmaf(xw[1][1][2], wq2, bq[oq]))) * scl;
            float q1 = fmaf(xw[2][1][0], wq0, fmaf(xw[2][1][1], wq1, fmaf(xw[2][1][2], wq2, bq[oq]))) * scl;
            float se0 = 0.f, ac0 = 0.f, se1 = 0.f, ac1 = 0.f;
#pragma unroll
            for (int j = 0; j < 9; ++j) {
                float e0 = __expf(q0 * kp[j]);
                se0 += e0; ac0 = fmaf(e0, vp[j], ac0);
                float e1 = __expf(q1 * kp[3 + j]);
                se1 += e1; ac1 = fmaf(e1, vp[3 + j], ac1);
            }
            ov0[cc] = fmaf(hwh, ac0 / se0, ov0[cc]);
            ov1[cc] = fmaf(hwh, ac1 / se1, ov1[cc]);
        }
    }
    __shared__ float s_part[128][6];
    if (hg == 1) {
#pragma unroll
        for (int cc = 0; cc < 3; ++cc) {
            s_part[slot][cc] = ov0[cc];
            s_part[slot][3 + cc] = ov1[cc];
        }
    }
    __syncthreads();
    if (hg == 0) {
        int pix = (y0 << 8) + xx;
        float* ob = out + bb * 196608;
#pragma unroll
        for (int cc = 0; cc < 3; ++cc) {
            ob[cc * 65536 + pix] = ov0[cc] + s_part[slot][cc];
            ob[cc * 65536 + pix + 256] = ov1[cc] + s_part[slot][3 + cc];
        }
    }
}

// ---------------- two-phase attention for p=2 / p=3, fp16 KV ----------------
// Phase 1: NO LDS, no barriers. Lane = tile (direct global gather), wave =
// uniform chunk of output groups. KV stored as fp16, group-major in 8-byte
// slots: kvh[g * T4 + t] = {half2, half2} (GSU=4 full, GSU=3 + 1 pad).
template<int P, int NH, int NWIN, int OFS, int GSU, int NCH>
__global__ __launch_bounds__(64 * NCH)
void proj3_pk(const float* __restrict__ x, const float* __restrict__ w,
              const float* __restrict__ bq, uint2* __restrict__ kv)
{
    constexpr int PP = P * P, L = 3 * PP, NO = NH * 9 * PP, NG = NO / GSU;
    constexpr int CPG = NG / NCH;
    constexpr int NT = NWIN + 2, T4 = 4 * NT * NT;
    int t = blockIdx.x * 64 + threadIdx.x;
    if (t >= T4) return;
    const int chunk = __builtin_amdgcn_readfirstlane((int)threadIdx.y);
    int bb = t / (NT * NT), rr = t - bb * NT * NT;
    int ty = rr / NT, tx = rr - ty * NT;
    const float* xb = x + bb * 196608;
    float xw[L];
#pragma unroll
    for (int i = 0; i < P; ++i) {
        int pr = refl256(ty * P + i - OFS) << 8;
#pragma unroll
        for (int j = 0; j < P; ++j) {
            int pc = refl256(tx * P + j - OFS);
#pragma unroll
            for (int c = 0; c < 3; ++c)
                xw[c * PP + i * P + j] = xb[c * 65536 + pr + pc];
        }
    }
    uint2* dst = kv + t + (size_t)chunk * CPG * T4;
#pragma unroll 1
    for (int g = 0; g < CPG; ++g) {
        int go = (chunk * CPG + g) * GSU;
        float acc[GSU];
#pragma unroll
        for (int e = 0; e < GSU; ++e) acc[e] = bq[go + e];
#pragma unroll
        for (int l = 0; l < L; ++l) {
            float xv = xw[l];
#pragma unroll
            for (int e = 0; e < GSU; ++e)
                acc[e] = fmaf(xv, w[(go + e) * L + l], acc[e]);
        }
        __half2 a01 = __floats2half2_rn(acc[0], acc[1]);
        __half2 a23 = __floats2half2_rn(acc[2], (GSU == 4) ? acc[GSU - 1] : 0.f);
        uint2 o;
        o.x = *(unsigned*)&a01;
        o.y = *(unsigned*)&a23;
        dst[(size_t)g * T4] = o;
    }
}

// Phase 2 (head-split): block = (128 window-slots, 2 head-groups of HPT).
// Per-group softmax-attention from fp16 global KV; combine via LDS partial.
template<int P, int NH, int NWIN, int OFS, int GSU, int HPT>
__global__ __launch_bounds__(256)
void attn3_pk(const uint2* __restrict__ kv, const float* __restrict__ hw,
              float* __restrict__ out)
{
    constexpr int PP = P * P, NT = NWIN + 2, T4 = 4 * NT * NT, PAD = OFS - P;
    constexpr int NGP = (PP + GSU - 1) / GSU;
    constexpr float SCL = (P == 2) ? 0.28867513459481287f : 0.19245008972987526f;
    constexpr float DD  = (P == 2) ? 0.6065306597126334f : 0.7165313105737893f; // exp(-1/P)
    float dpw[2 * P - 1];
    dpw[0] = 1.f;
#pragma unroll
    for (int k = 1; k < 2 * P - 1; ++k) dpw[k] = dpw[k - 1] * DD;

    const int slot = threadIdx.x;                       // 0..127
    const int hg = __builtin_amdgcn_readfirstlane((int)threadIdx.y);
    int wlin = blockIdx.x * 128 + slot;
    const bool active = wlin < 4 * NWIN * NWIN;
    int wsafe = active ? wlin : 0;
    int c = blockIdx.y;
    int bb = wsafe / (NWIN * NWIN); int rr = wsafe - bb * (NWIN * NWIN);
    int yy = rr / NWIN, xx = rr - yy * NWIN;
    int tbase = bb * NT * NT + yy * NT + xx;
    int tn[9];
#pragma unroll
    for (int di = 0; di < 3; ++di)
#pragma unroll
        for (int dj = 0; dj < 3; ++dj) tn[di * 3 + dj] = tbase + di * NT + dj;
    float oa[PP];
#pragma unroll
    for (int e = 0; e < PP; ++e) oa[e] = 0.f;
#pragma unroll 1
    for (int hi = 0; hi < HPT; ++hi) {
        int h = hg * HPT + hi;
        int oq = ((h * 3 + 0) * 3 + c) * PP;
        int ok = ((h * 3 + 1) * 3 + c) * PP;
        int ov = ((h * 3 + 2) * 3 + c) * PP;
        int gq = oq / GSU, gk = ok / GSU, gv = ov / GSU;
        float q[PP];
#pragma unroll
        for (int u = 0; u < NGP; ++u) {
            float g4[4];
            unpack4h(kv[(size_t)(gq + u) * T4 + tn[4]], g4);
#pragma unroll
            for (int e = 0; e < GSU; ++e) q[u * GSU + e] = g4[e];
        }
        float sc[9];
#pragma unroll
        for (int j = 0; j < 9; ++j) {
            int di = j / 3, dj = j - di * 3;
            float s = 0.f;
#pragma unroll
            for (int u = 0; u < NGP; ++u) {
                float g4[4];
                unpack4h(kv[(size_t)(gk + u) * T4 + tn[j]], g4);
#pragma unroll
                for (int e = 0; e < GSU; ++e) {
                    int Pp = u * GSU + e;
                    int i = Pp / P, jj = Pp - i * P;
                    int er = (di == 0) ? (P - 1 - i) : (di == 2 ? i : 0);
                    int ec = (dj == 0) ? (P - 1 - jj) : (dj == 2 ? jj : 0);
                    s = fmaf(q[Pp] * g4[e], dpw[er + ec], s);
                }
            }
            sc[j] = s * SCL;
        }
        float se = 0.f;
#pragma unroll
        for (int j = 0; j < 9; ++j) { sc[j] = __expf(sc[j]); se += sc[j]; }
        float tmp[PP];
#pragma unroll
        for (int e = 0; e < PP; ++e) tmp[e] = 0.f;
#pragma unroll
        for (int j = 0; j < 9; ++j) {
#pragma unroll
            for (int u = 0; u < NGP; ++u) {
                float g4[4];
                unpack4h(kv[(size_t)(gv + u) * T4 + tn[j]], g4);
#pragma unroll
                for (int e = 0; e < GSU; ++e)
                    tmp[u * GSU + e] = fmaf(sc[j], g4[e], tmp[u * GSU + e]);
            }
        }
        float f = hw[h] / se;
#pragma unroll
        for (int e = 0; e < PP; ++e) oa[e] = fmaf(f, tmp[e], oa[e]);
    }
    __shared__ float s_part[128][PP];
    if (hg == 1) {
#pragma unroll
        for (int e = 0; e < PP; ++e) s_part[slot][e] = oa[e];
    }
    __syncthreads();
    if (hg == 0 && active) {
        float* ob = out + (bb * 3 + c) * 65536;
#pragma unroll
        for (int i = 0; i < P; ++i) {
            int r = yy * P + i - PAD;
            if (PAD && r < 0) continue;
#pragma unroll
            for (int jj = 0; jj < P; ++jj) {
                int col = xx * P + jj - PAD;
                if (PAD && col < 0) continue;
                int e = i * P + jj;
                ob[(r << 8) + col] = oa[e] + s_part[slot][e];
            }
        }
    }
}

// -------- conv0 (5x5, 9->3, pad 2) + final, source-split over y ------------
__global__ __launch_bounds__(384)
void conv_finalv3(const float* __restrict__ x, const float* __restrict__ x9,
                  const float* __restrict__ x6, const float* __restrict__ x3,
                  const float* __restrict__ cw, const float* __restrict__ cb,
                  const float* __restrict__ pmax, float* __restrict__ out)
{
    const int slot = threadIdx.x;                       // 0..127
    const int src = __builtin_amdgcn_readfirstlane((int)threadIdx.y);  // 0,1,2
    int bb = blockIdx.x >> 8;                           // 1024 blocks, 256/batch
    __shared__ float s_g;
    {
        int flat = threadIdx.y * 128 + slot;
        if (flat < 64) {
            const float* pm = pmax + bb * 256 + flat * 4;
            float v = fmaxf(fmaxf(pm[0], pm[1]), fmaxf(pm[2], pm[3]));
#pragma unroll
            for (int off = 32; off > 0; off >>= 1)
                v = fmaxf(v, __shfl_down(v, off, 64));
            if (flat == 0) s_g = v;
        }
    }
    int pair = (blockIdx.x & 255) * 128 + slot;         // within batch
    int xp = (pair & 127) << 1, r = pair >> 7;
    float a[3][2];
#pragma unroll
    for (int oc = 0; oc < 3; ++oc) { a[oc][0] = 0.f; a[oc][1] = 0.f; }
    const float* bp = (src == 0 ? x9 : (src == 1 ? x6 : x3)) + bb * 196608;
#pragma unroll 1
    for (int c2 = 0; c2 < 3; ++c2) {
        const float* pl = bp + c2 * 65536;
        const float* wp = cw + (src * 3 + c2) * 25;     // wave-uniform -> s_load
#pragma unroll
        for (int ky = 0; ky < 5; ++ky) {
            int rr = r + ky - 2;
            if ((unsigned)rr >= 256u) continue;
            const float* row = pl + (rr << 8);
            float2 va = (xp >= 2) ? *(const float2*)(row + xp - 2)
                                  : make_float2(0.f, 0.f);
            float2 vb = *(const float2*)(row + xp);
            float2 vc = (xp + 2 < 256) ? *(const float2*)(row + xp + 2)
                                       : make_float2(0.f, 0.f);
            float cv[6] = {va.x, va.y, vb.x, vb.y, vc.x, vc.y};
#pragma unroll
            for (int kx = 0; kx < 5; ++kx) {
                float w0 = wp[ky * 5 + kx];
                float w1 = wp[225 + ky * 5 + kx];
                float w2 = wp[450 + ky * 5 + kx];
                float v0 = cv[kx], v1 = cv[kx + 1];
                a[0][0] = fmaf(v0, w0, a[0][0]); a[0][1] = fmaf(v1, w0, a[0][1]);
                a[1][0] = fmaf(v0, w1, a[1][0]); a[1][1] = fmaf(v1, w1, a[1][1]);
                a[2][0] = fmaf(v0, w2, a[2][0]); a[2][1] = fmaf(v1, w2, a[2][1]);
            }
        }
    }
    __shared__ float s_part[2][128][6];
    if (src > 0) {
#pragma unroll
        for (int oc = 0; oc < 3; ++oc) {
            s_part[src - 1][slot][oc * 2]     = a[oc][0];
            s_part[src - 1][slot][oc * 2 + 1] = a[oc][1];
        }
    }
    __syncthreads();
    if (src == 0) {
        float g = s_g;
        int pix = (r << 8) + xp;
        const float* xb = x + bb * 196608;
        float* ob = out + bb * 196608;
#pragma unroll
        for (int oc = 0; oc < 3; ++oc) {
            float a0 = a[oc][0] + s_part[0][slot][oc * 2] + s_part[1][slot][oc * 2] + cb[oc];
            float a1 = a[oc][1] + s_part[0][slot][oc * 2 + 1] + s_part[1][slot][oc * 2 + 1] + cb[oc];
            float2 xv = *(const float2*)(xb + oc * 65536 + pix);
            float2 o2;
            float x0;
            x0 = fmaxf(a0, 0.f); o2.x = fmaxf(xv.x * x0 + g - x0, 0.f);
            x0 = fmaxf(a1, 0.f); o2.y = fmaxf(xv.y * x0 + g - x0, 0.f);
            *(float2*)(ob + oc * 65536 + pix) = o2;
        }
    }
}

extern "C" void kernel_launch(void* const* d_in, const int* in_sizes, int n_in,
                              void* d_out, int out_size, void* d_ws, size_t ws_size,
                              hipStream_t stream)
{
    const float* x   = (const float*)d_in[0];
    const float* w3  = (const float*)d_in[1];
    const float* b3  = (const float*)d_in[2];
    const float* hw3 = (const float*)d_in[3];
    const float* w6  = (const float*)d_in[4];
    const float* b6  = (const float*)d_in[5];
    const float* hw6 = (const float*)d_in[6];
    const float* w9  = (const float*)d_in[7];
    const float* b9  = (const float*)d_in[8];
    const float* hw9 = (const float*)d_in[9];
    const float* cw  = (const float*)d_in[10];
    const float* cb  = (const float*)d_in[11];

    float* ws   = (float*)d_ws;
    float* x3b  = ws;                     // 786432 floats
    float* x6b  = ws + 786432;            // 786432
    float* x9b  = ws + 1572864;           // 786432
    float* pmax = ws + 2359296;           // 1024
    uint2* kvb  = (uint2*)(ws + 2360320); // fp16 KV: up to 36*67600*8 B = 19.5 MB
    float* out  = (float*)d_out;

    // stage 1 (p=1), head-split, + fused batch-max partials
    attn_p1v2<<<1024, dim3(128, 2), 0, stream>>>(x, w3, b3, hw3, x3b, pmax);

    // stage 2: p=2, NH=4, NWIN=128, OFS=2, GSU=4, NG=36, NCH=6 -> CPG=6
    proj3_pk<2, 4, 128, 2, 4, 6><<<1057, dim3(64, 6), 0, stream>>>(x3b, w6, b6, kvb);
    attn3_pk<2, 4, 128, 2, 4, 2><<<dim3(512, 3), dim3(128, 2), 0, stream>>>(kvb, hw6, x6b);
    // stage 3: p=3, NH=2, NWIN=86, OFS=5, GSU=3, NG=54, NCH=9 -> CPG=6
    proj3_pk<3, 2, 86, 5, 3, 9><<<484, dim3(64, 9), 0, stream>>>(x6b, w9, b9, kvb);
    attn3_pk<3, 2, 86, 5, 3, 1><<<dim3(232, 3), dim3(128, 2), 0, stream>>>(kvb, hw9, x9b);

    conv_finalv3<<<1024, dim3(128, 3), 0, stream>>>(x, x9b, x6b, x3b, cw, cb, pmax, out);
}

// Round 10
// 151.374 us; speedup vs baseline: 1.4376x; 1.0274x over previous
//
#include <hip/hip_runtime.h>
#include <hip/hip_fp16.h>
#include <math.h>

__device__ __forceinline__ int refl256(int t) {
    t = t < 0 ? -t : t;
    return t > 255 ? 510 - t : t;
}

__device__ __forceinline__ void unpack4h(uint2 u, float* g4) {
    __half2 h01 = *(__half2*)&u.x, h23 = *(__half2*)&u.y;
    g4[0] = __low2float(h01); g4[1] = __high2float(h01);
    g4[2] = __low2float(h23); g4[3] = __high2float(h23);
}
__device__ __forceinline__ void unpack8h(uint4 u, float* k4, float* v4) {
    __half2 a = *(__half2*)&u.x, b = *(__half2*)&u.y;
    __half2 c = *(__half2*)&u.z, d = *(__half2*)&u.w;
    k4[0] = __low2float(a); k4[1] = __high2float(a);
    k4[2] = __low2float(b); k4[3] = __high2float(b);
    v4[0] = __low2float(c); v4[1] = __high2float(c);
    v4[2] = __low2float(d); v4[3] = __high2float(d);
}

// ---------------- stage 1: p=1, NH=6, 2x2 quad + head-split over y ---------
// Thread = 2x2 pixel quad; 16 shared k/v projection positions serve 4 pixels
// (4 positions/px vs 6 for the row-pair version). hg splits heads 2-way.
__global__ __launch_bounds__(256)
void attn_p1q(const float* __restrict__ x, const float* __restrict__ w,
              const float* __restrict__ bq, const float* __restrict__ hw,
              float* __restrict__ out, float* __restrict__ pmax)
{
    const int slot = threadIdx.x;                      // 0..127
    const int hg = __builtin_amdgcn_readfirstlane((int)threadIdx.y);
    int t2 = blockIdx.x * 128 + slot;                  // 65536 quads
    int qx = t2 & 127, qy = (t2 >> 7) & 127, bb = t2 >> 14;
    int x0 = qx * 2, y0 = qy * 2;
    const float* xb = x + bb * 196608;
    int rs[4], cs[4];
#pragma unroll
    for (int d = 0; d < 4; ++d) {
        rs[d] = refl256(y0 + d - 1) << 8;
        cs[d] = refl256(x0 + d - 1);
    }
    float xw[4][4][3];
#pragma unroll
    for (int dr = 0; dr < 4; ++dr)
#pragma unroll
        for (int dc = 0; dc < 4; ++dc)
#pragma unroll
            for (int c = 0; c < 3; ++c)
                xw[dr][dc][c] = xb[c * 65536 + rs[dr] + cs[dc]];

    // fused batch-max partial (own pixels = rows 1,2 x cols 1,2)
    {
        float bm = 0.f;
#pragma unroll
        for (int c = 0; c < 3; ++c) {
            bm = fmaxf(bm, fmaxf(xw[1][1][c], xw[1][2][c]));
            bm = fmaxf(bm, fmaxf(xw[2][1][c], xw[2][2][c]));
        }
#pragma unroll
        for (int off = 32; off > 0; off >>= 1)
            bm = fmaxf(bm, __shfl_down(bm, off, 64));
        __shared__ float sm[4];
        int flat = threadIdx.y * 128 + slot;
        if ((flat & 63) == 0) sm[flat >> 6] = bm;
        __syncthreads();
        if (flat == 0)
            pmax[blockIdx.x] = fmaxf(fmaxf(sm[0], sm[1]), fmaxf(sm[2], sm[3]));
    }

    float ov[2][2][3];
#pragma unroll
    for (int py = 0; py < 2; ++py)
#pragma unroll
        for (int px = 0; px < 2; ++px)
#pragma unroll
            for (int c = 0; c < 3; ++c) ov[py][px][c] = 0.f;
    const float scl = 0.57735026919f;  // 1/sqrt(3); bias == 1 for p=1
#pragma unroll 1
    for (int hi = 0; hi < 3; ++hi) {
        int h = hg * 3 + hi;
        float hwh = hw[h];
#pragma unroll
        for (int cc = 0; cc < 3; ++cc) {
            int oq = 9 * h + cc, ok = oq + 3, oV = oq + 6;
            float wq0 = w[oq * 3], wq1 = w[oq * 3 + 1], wq2 = w[oq * 3 + 2];
            float wk0 = w[ok * 3], wk1 = w[ok * 3 + 1], wk2 = w[ok * 3 + 2];
            float wv0 = w[oV * 3], wv1 = w[oV * 3 + 1], wv2 = w[oV * 3 + 2];
            float bqq = bq[oq], bk = bq[ok], bv = bq[oV];
            float kp[16], vp[16];
#pragma unroll
            for (int pos = 0; pos < 16; ++pos) {
                const float* xv = xw[pos >> 2][pos & 3];
                kp[pos] = fmaf(xv[0], wk0, fmaf(xv[1], wk1, fmaf(xv[2], wk2, bk)));
                vp[pos] = fmaf(xv[0], wv0, fmaf(xv[1], wv1, fmaf(xv[2], wv2, bv)));
            }
#pragma unroll
            for (int py = 0; py < 2; ++py)
#pragma unroll
                for (int px = 0; px < 2; ++px) {
                    const float* xc = xw[1 + py][1 + px];
                    float q = fmaf(xc[0], wq0, fmaf(xc[1], wq1, fmaf(xc[2], wq2, bqq))) * scl;
                    float se = 0.f, ac = 0.f;
#pragma unroll
                    for (int dr = 0; dr < 3; ++dr)
#pragma unroll
                        for (int dc = 0; dc < 3; ++dc) {
                            int pos = (py + dr) * 4 + (px + dc);
                            float e0 = __expf(q * kp[pos]);
                            se += e0; ac = fmaf(e0, vp[pos], ac);
                        }
                    ov[py][px][cc] = fmaf(hwh, ac / se, ov[py][px][cc]);
                }
        }
    }
    __shared__ float s_part[128][12];
    if (hg == 1) {
#pragma unroll
        for (int py = 0; py < 2; ++py)
#pragma unroll
            for (int px = 0; px < 2; ++px)
#pragma unroll
                for (int cc = 0; cc < 3; ++cc)
                    s_part[slot][(py * 2 + px) * 3 + cc] = ov[py][px][cc];
    }
    __syncthreads();
    if (hg == 0) {
        float* ob = out + bb * 196608;
#pragma unroll
        for (int cc = 0; cc < 3; ++cc)
#pragma unroll
            for (int py = 0; py < 2; ++py) {
                float2 o2;
                o2.x = ov[py][0][cc] + s_part[slot][(py * 2 + 0) * 3 + cc];
                o2.y = ov[py][1][cc] + s_part[slot][(py * 2 + 1) * 3 + cc];
                *(float2*)(ob + cc * 65536 + ((y0 + py) << 8) + x0) = o2;
            }
    }
}

// ---------------- two-phase attention for p=2 / p=3, fp16 KV ----------------
// Phase 1: lane = tile (direct gather), wave = uniform stride over slot tasks.
// q-slots -> uint2 kvq[s*T4+t]; interleaved k|v slots -> uint4 kvv[s*T4+t].
template<int P, int NH, int NWIN, int OFS, int GSU, int NCH>
__global__ __launch_bounds__(64 * NCH)
void proj4_pk(const float* __restrict__ x, const float* __restrict__ w,
              const float* __restrict__ bq,
              uint2* __restrict__ kvq, uint4* __restrict__ kvv)
{
    constexpr int PP = P * P, L = 3 * PP, NGP = PP / GSU;
    constexpr int QS = NH * 3 * NGP, TOT = 2 * QS;
    constexpr int NT = NWIN + 2, T4 = 4 * NT * NT;
    int t = blockIdx.x * 64 + threadIdx.x;
    if (t >= T4) return;
    const int wvi = __builtin_amdgcn_readfirstlane((int)threadIdx.y);
    int bb = t / (NT * NT), rr = t - bb * NT * NT;
    int ty = rr / NT, tx = rr - ty * NT;
    const float* xb = x + bb * 196608;
    float xw[L];
#pragma unroll
    for (int i = 0; i < P; ++i) {
        int pr = refl256(ty * P + i - OFS) << 8;
#pragma unroll
        for (int j = 0; j < P; ++j) {
            int pc = refl256(tx * P + j - OFS);
#pragma unroll
            for (int c = 0; c < 3; ++c)
                xw[c * PP + i * P + j] = xb[c * 65536 + pr + pc];
        }
    }
#pragma unroll 1
    for (int s = wvi; s < TOT; s += NCH) {
        int sq = (s < QS) ? s : s - QS;
        int h = sq / (3 * NGP);
        int rem = sq - h * (3 * NGP);
        int c = rem / NGP, u = rem - c * NGP;
        if (s < QS) {
            int ob = ((h * 3 + 0) * 3 + c) * PP + u * GSU;
            float acc[GSU];
#pragma unroll
            for (int e = 0; e < GSU; ++e) acc[e] = bq[ob + e];
#pragma unroll
            for (int l = 0; l < L; ++l) {
                float xv = xw[l];
#pragma unroll
                for (int e = 0; e < GSU; ++e)
                    acc[e] = fmaf(xv, w[(ob + e) * L + l], acc[e]);
            }
            __half2 a01 = __floats2half2_rn(acc[0], acc[1]);
            __half2 a23 = __floats2half2_rn(GSU > 2 ? acc[2] : 0.f,
                                            GSU > 3 ? acc[GSU - 1] : 0.f);
            uint2 o;
            o.x = *(unsigned*)&a01;
            o.y = *(unsigned*)&a23;
            kvq[(size_t)sq * T4 + t] = o;
        } else {
            int okb = ((h * 3 + 1) * 3 + c) * PP + u * GSU;
            int ovb = ((h * 3 + 2) * 3 + c) * PP + u * GSU;
            float ak[GSU], av[GSU];
#pragma unroll
            for (int e = 0; e < GSU; ++e) { ak[e] = bq[okb + e]; av[e] = bq[ovb + e]; }
#pragma unroll
            for (int l = 0; l < L; ++l) {
                float xv = xw[l];
#pragma unroll
                for (int e = 0; e < GSU; ++e) {
                    ak[e] = fmaf(xv, w[(okb + e) * L + l], ak[e]);
                    av[e] = fmaf(xv, w[(ovb + e) * L + l], av[e]);
                }
            }
            __half2 k01 = __floats2half2_rn(ak[0], ak[1]);
            __half2 k23 = __floats2half2_rn(GSU > 2 ? ak[2] : 0.f,
                                            GSU > 3 ? ak[GSU - 1] : 0.f);
            __half2 v01 = __floats2half2_rn(av[0], av[1]);
            __half2 v23 = __floats2half2_rn(GSU > 2 ? av[2] : 0.f,
                                            GSU > 3 ? av[GSU - 1] : 0.f);
            uint4 o;
            o.x = *(unsigned*)&k01;
            o.y = *(unsigned*)&k23;
            o.z = *(unsigned*)&v01;
            o.w = *(unsigned*)&v23;
            kvv[(size_t)sq * T4 + t] = o;
        }
    }
}

// Phase 2: single-pass unnormalized softmax; one 16B load gives k AND v.
template<int P, int NH, int NWIN, int OFS, int GSU, int HPT>
__global__ __launch_bounds__(256)
void attn4_pk(const uint2* __restrict__ kvq, const uint4* __restrict__ kvv,
              const float* __restrict__ hw, float* __restrict__ out)
{
    constexpr int PP = P * P, NGP = PP / GSU;
    constexpr int NT = NWIN + 2, T4 = 4 * NT * NT, PAD = OFS - P;
    constexpr float SCL = (P == 2) ? 0.28867513459481287f : 0.19245008972987526f;
    constexpr float DD  = (P == 2) ? 0.6065306597126334f : 0.7165313105737893f; // exp(-1/P)
    float dpw[2 * P - 1];
    dpw[0] = 1.f;
#pragma unroll
    for (int k = 1; k < 2 * P - 1; ++k) dpw[k] = dpw[k - 1] * DD;

    const int slot = threadIdx.x;                       // 0..127
    const int hg = __builtin_amdgcn_readfirstlane((int)threadIdx.y);
    int wlin = blockIdx.x * 128 + slot;
    const bool active = wlin < 4 * NWIN * NWIN;
    int wsafe = active ? wlin : 0;
    int c = blockIdx.y;
    int bb = wsafe / (NWIN * NWIN); int rr = wsafe - bb * (NWIN * NWIN);
    int yy = rr / NWIN, xx = rr - yy * NWIN;
    int tbase = bb * NT * NT + yy * NT + xx;
    int tn[9];
#pragma unroll
    for (int di = 0; di < 3; ++di)
#pragma unroll
        for (int dj = 0; dj < 3; ++dj) tn[di * 3 + dj] = tbase + di * NT + dj;
    float oa[PP];
#pragma unroll
    for (int e = 0; e < PP; ++e) oa[e] = 0.f;
#pragma unroll 1
    for (int hi = 0; hi < HPT; ++hi) {
        int h = hg * HPT + hi;
        int sb = (h * 3 + c) * NGP;
        float q[PP];
#pragma unroll
        for (int u = 0; u < NGP; ++u) {
            float g4[4];
            unpack4h(kvq[(size_t)(sb + u) * T4 + tn[4]], g4);
#pragma unroll
            for (int e = 0; e < GSU; ++e) q[u * GSU + e] = g4[e];
        }
        float se = 0.f;
        float tmp[PP];
#pragma unroll
        for (int e = 0; e < PP; ++e) tmp[e] = 0.f;
#pragma unroll
        for (int j = 0; j < 9; ++j) {
            int di = j / 3, dj = j - di * 3;
            float vreg[PP];
            float s = 0.f;
#pragma unroll
            for (int u = 0; u < NGP; ++u) {
                float k4[4], v4[4];
                unpack8h(kvv[(size_t)(sb + u) * T4 + tn[j]], k4, v4);
#pragma unroll
                for (int e = 0; e < GSU; ++e) {
                    int Pp = u * GSU + e;
                    int i = Pp / P, jj = Pp - i * P;
                    int er = (di == 0) ? (P - 1 - i) : (di == 2 ? i : 0);
                    int ec = (dj == 0) ? (P - 1 - jj) : (dj == 2 ? jj : 0);
                    s = fmaf(q[Pp] * k4[e], dpw[er + ec], s);
                    vreg[Pp] = v4[e];
                }
            }
            float e2 = __expf(s * SCL);
            se += e2;
#pragma unroll
            for (int e = 0; e < PP; ++e) tmp[e] = fmaf(e2, vreg[e], tmp[e]);
        }
        float f = hw[h] / se;
#pragma unroll
        for (int e = 0; e < PP; ++e) oa[e] = fmaf(f, tmp[e], oa[e]);
    }
    __shared__ float s_part[128][PP];
    if (hg == 1) {
#pragma unroll
        for (int e = 0; e < PP; ++e) s_part[slot][e] = oa[e];
    }
    __syncthreads();
    if (hg == 0 && active) {
        float* ob = out + (bb * 3 + c) * 65536;
#pragma unroll
        for (int i = 0; i < P; ++i) {
            int r = yy * P + i - PAD;
            if (PAD && r < 0) continue;
#pragma unroll
            for (int jj = 0; jj < P; ++jj) {
                int col = xx * P + jj - PAD;
                if (PAD && col < 0) continue;
                int e = i * P + jj;
                ob[(r << 8) + col] = oa[e] + s_part[slot][e];
            }
        }
    }
}

// -------- conv0 (5x5, 9->3, pad 2) + final, source-split over y ------------
__global__ __launch_bounds__(384)
void conv_finalv3(const float* __restrict__ x, const float* __restrict__ x9,
                  const float* __restrict__ x6, const float* __restrict__ x3,
                  const float* __restrict__ cw, const float* __restrict__ cb,
                  const float* __restrict__ pmax, float* __restrict__ out)
{
    const int slot = threadIdx.x;                       // 0..127
    const int src = __builtin_amdgcn_readfirstlane((int)threadIdx.y);  // 0,1,2
    int bb = blockIdx.x >> 8;                           // 1024 blocks, 256/batch
    __shared__ float s_g;
    {
        int flat = threadIdx.y * 128 + slot;
        if (flat < 32) {                                // 128 partials per batch
            const float* pm = pmax + bb * 128 + flat * 4;
            float v = fmaxf(fmaxf(pm[0], pm[1]), fmaxf(pm[2], pm[3]));
#pragma unroll
            for (int off = 16; off > 0; off >>= 1)
                v = fmaxf(v, __shfl_down(v, off, 64));
            if (flat == 0) s_g = v;
        }
    }
    int pair = (blockIdx.x & 255) * 128 + slot;         // within batch
    int xp = (pair & 127) << 1, r = pair >> 7;
    float a[3][2];
#pragma unroll
    for (int oc = 0; oc < 3; ++oc) { a[oc][0] = 0.f; a[oc][1] = 0.f; }
    const float* bp = (src == 0 ? x9 : (src == 1 ? x6 : x3)) + bb * 196608;
#pragma unroll 1
    for (int c2 = 0; c2 < 3; ++c2) {
        const float* pl = bp + c2 * 65536;
        const float* wp = cw + (src * 3 + c2) * 25;     // wave-uniform -> s_load
#pragma unroll
        for (int ky = 0; ky < 5; ++ky) {
            int rr = r + ky - 2;
            if ((unsigned)rr >= 256u) continue;
            const float* row = pl + (rr << 8);
            float2 va = (xp >= 2) ? *(const float2*)(row + xp - 2)
                                  : make_float2(0.f, 0.f);
            float2 vb = *(const float2*)(row + xp);
            float2 vc = (xp + 2 < 256) ? *(const float2*)(row + xp + 2)
                                       : make_float2(0.f, 0.f);
            float cv[6] = {va.x, va.y, vb.x, vb.y, vc.x, vc.y};
#pragma unroll
            for (int kx = 0; kx < 5; ++kx) {
                float w0 = wp[ky * 5 + kx];
                float w1 = wp[225 + ky * 5 + kx];
                float w2 = wp[450 + ky * 5 + kx];
                float v0 = cv[kx], v1 = cv[kx + 1];
                a[0][0] = fmaf(v0, w0, a[0][0]); a[0][1] = fmaf(v1, w0, a[0][1]);
                a[1][0] = fmaf(v0, w1, a[1][0]); a[1][1] = fmaf(v1, w1, a[1][1]);
                a[2][0] = fmaf(v0, w2, a[2][0]); a[2][1] = fmaf(v1, w2, a[2][1]);
            }
        }
    }
    __shared__ float s_part[2][128][6];
    if (src > 0) {
#pragma unroll
        for (int oc = 0; oc < 3; ++oc) {
            s_part[src - 1][slot][oc * 2]     = a[oc][0];
            s_part[src - 1][slot][oc * 2 + 1] = a[oc][1];
        }
    }
    __syncthreads();
    if (src == 0) {
        float g = s_g;
        int pix = (r << 8) + xp;
        const float* xb = x + bb * 196608;
        float* ob = out + bb * 196608;
#pragma unroll
        for (int oc = 0; oc < 3; ++oc) {
            float a0 = a[oc][0] + s_part[0][slot][oc * 2] + s_part[1][slot][oc * 2] + cb[oc];
            float a1 = a[oc][1] + s_part[0][slot][oc * 2 + 1] + s_part[1][slot][oc * 2 + 1] + cb[oc];
            float2 xv = *(const float2*)(xb + oc * 65536 + pix);
            float2 o2;
            float x0;
            x0 = fmaxf(a0, 0.f); o2.x = fmaxf(xv.x * x0 + g - x0, 0.f);
            x0 = fmaxf(a1, 0.f); o2.y = fmaxf(xv.y * x0 + g - x0, 0.f);
            *(float2*)(ob + oc * 65536 + pix) = o2;
        }
    }
}

extern "C" void kernel_launch(void* const* d_in, const int* in_sizes, int n_in,
                              void* d_out, int out_size, void* d_ws, size_t ws_size,
                              hipStream_t stream)
{
    const float* x   = (const float*)d_in[0];
    const float* w3  = (const float*)d_in[1];
    const float* b3  = (const float*)d_in[2];
    const float* hw3 = (const float*)d_in[3];
    const float* w6  = (const float*)d_in[4];
    const float* b6  = (const float*)d_in[5];
    const float* hw6 = (const float*)d_in[6];
    const float* w9  = (const float*)d_in[7];
    const float* b9  = (const float*)d_in[8];
    const float* hw9 = (const float*)d_in[9];
    const float* cw  = (const float*)d_in[10];
    const float* cb  = (const float*)d_in[11];

    float* ws   = (float*)d_ws;
    float* x3b  = ws;                     // 786432 floats
    float* x6b  = ws + 786432;            // 786432
    float* x9b  = ws + 1572864;           // 786432
    float* pmax = ws + 2359296;           // 512
    uint2* kvq  = (uint2*)(ws + 2360320); // q slots: <= 12*67600*8 B = 6.5 MB
    uint4* kvv  = (uint4*)(ws + 3982720); // k|v slots: <= 12*67600*16 B = 13 MB
    float* out  = (float*)d_out;

    // stage 1 (p=1), 2x2 quads, head-split, + fused batch-max partials
    attn_p1q<<<512, dim3(128, 2), 0, stream>>>(x, w3, b3, hw3, x3b, pmax);

    // stage 2: p=2, NH=4, NWIN=128, OFS=2, GSU=4 (NGP=1), NCH=6
    proj4_pk<2, 4, 128, 2, 4, 6><<<1057, dim3(64, 6), 0, stream>>>(x3b, w6, b6, kvq, kvv);
    attn4_pk<2, 4, 128, 2, 4, 2><<<dim3(512, 3), dim3(128, 2), 0, stream>>>(kvq, kvv, hw6, x6b);
    // stage 3: p=3, NH=2, NWIN=86, OFS=5, GSU=3 (NGP=3), NCH=9
    proj4_pk<3, 2, 86, 5, 3, 9><<<484, dim3(64, 9), 0, stream>>>(x6b, w9, b9, kvq, kvv);
    attn4_pk<3, 2, 86, 5, 3, 1><<<dim3(232, 3), dim3(128, 2), 0, stream>>>(kvq, kvv, hw9, x9b);

    conv_finalv3<<<1024, dim3(128, 3), 0, stream>>>(x, x9b, x6b, x3b, cw, cb, pmax, out);
}